// Round 13
// baseline (1486.414 us; speedup 1.0000x reference)
//
#include <hip/hip_runtime.h>
#include <hip/hip_bf16.h>
#include <math.h>

using u16 = unsigned short;
typedef __attribute__((ext_vector_type(8))) short short8;
typedef __attribute__((ext_vector_type(8))) _Float16 half8;
typedef __attribute__((ext_vector_type(4))) float f32x4;
typedef __attribute__((ext_vector_type(4))) u16 u16x4;

__device__ __constant__ int c_OFF[9] = {0, 119, 123, 135, 147, 157, 163, 169, 171};

__device__ __forceinline__ float h2f(u16 u) {
    _Float16 h;
    __builtin_memcpy(&h, &u, 2);
    return (float)h;
}
__device__ __forceinline__ u16 f2h(float f) {
    _Float16 h = (_Float16)f;
    u16 u;
    __builtin_memcpy(&u, &h, 2);
    return u;
}
__device__ __forceinline__ float sigf(float x) { return 1.f / (1.f + expf(-x)); }

// ---------------- diagnostics ----------------
__global__ void k_diagf(float* out, int G, float val) {
    int i = blockIdx.x * 256 + threadIdx.x;
    if (i < G) out[i] = val;
}

// ---------------- zero helpers ----------------
__global__ void k_zero_f32(float* p, int n) {
    int i = blockIdx.x * 256 + threadIdx.x;
    if (i < n) p[i] = 0.f;
}
__global__ void k_zero_u16(u16* p, int n) {
    int i = blockIdx.x * 256 + threadIdx.x;
    if (i < n) p[i] = 0;
}
__global__ void k_zero_int(int* p, int n) {
    int i = blockIdx.x * 256 + threadIdx.x;
    if (i < n) p[i] = 0;
}

// ---------------- fp32 -> fp16 convert ----------------
__global__ void k_cvtW(const float* __restrict__ src, u16* __restrict__ dst, int n) {
    int i = blockIdx.x * 256 + threadIdx.x;
    if (i < n) dst[i] = f2h(src[i]);
}

// ---------------- atom encoder: 8 nodes/block, 8 cols/thread, vectorized ----------------
__global__ __launch_bounds__(256) void k_embed(const int* __restrict__ x,
                                               const float* __restrict__ emb,
                                               u16* __restrict__ out, int N) {
    __shared__ int rows[72];
    int nb = blockIdx.x * 8;
    int tid = threadIdx.x;
    if (tid < 72) rows[tid] = x[(size_t)nb * 9 + tid] + c_OFF[tid % 9];
    __syncthreads();
    int ln = tid >> 5;
    int c8 = (tid & 31) * 8;
    float s0 = 0.f, s1 = 0.f, s2 = 0.f, s3 = 0.f, s4 = 0.f, s5 = 0.f, s6 = 0.f, s7 = 0.f;
#pragma unroll
    for (int c = 0; c < 9; ++c) {
        int r = rows[ln * 9 + c];
        f32x4 a = *(const f32x4*)&emb[r * 256 + c8];
        f32x4 b = *(const f32x4*)&emb[r * 256 + c8 + 4];
        s0 += a[0]; s1 += a[1]; s2 += a[2]; s3 += a[3];
        s4 += b[0]; s5 += b[1]; s6 += b[2]; s7 += b[3];
    }
    short8 o;
    o[0] = (short)f2h(s0); o[1] = (short)f2h(s1); o[2] = (short)f2h(s2); o[3] = (short)f2h(s3);
    o[4] = (short)f2h(s4); o[5] = (short)f2h(s5); o[6] = (short)f2h(s6); o[7] = (short)f2h(s7);
    *(short8*)&out[(size_t)(nb + ln) * 256 + c8] = o;
}

// ---------------- graph segment starts from sorted batch ----------------
__global__ void k_gstart(const int* __restrict__ batch, int* __restrict__ gstart, int N, int G) {
    int i = blockIdx.x * 256 + threadIdx.x;
    if (i >= N) return;
    int b = batch[i];
    if (i == 0) {
        for (int g = 0; g <= b; ++g) gstart[g] = 0;
    } else {
        int p = batch[i - 1];
        for (int g = p + 1; g <= b; ++g) gstart[g] = i;
    }
    if (i == N - 1) {
        for (int g = b + 1; g <= G; ++g) gstart[g] = N;
    }
}

// ---------------- CSR build (in-place in rp) ----------------
__global__ void k_count(const int* __restrict__ tgt, int* rp, int E) {
    int e = blockIdx.x * 256 + threadIdx.x;
    if (e < E) atomicAdd(&rp[tgt[e]], 1);
}

__global__ void k_dinv(const int* __restrict__ cnt, float* __restrict__ dinv, int N) {
    int i = blockIdx.x * 256 + threadIdx.x;
    if (i < N) dinv[i] = rsqrtf((float)cnt[i] + 1.f);
}

__global__ void k_scan1(int* __restrict__ rp, int* __restrict__ bsum, int N) {
    int t = threadIdx.x;
    int base = blockIdx.x * 1024 + t * 4;
    int v0 = 0, v1 = 0, v2 = 0, v3 = 0;
    if (base + 3 < N) {
        v0 = rp[base]; v1 = rp[base + 1]; v2 = rp[base + 2]; v3 = rp[base + 3];
    } else {
        if (base < N) v0 = rp[base];
        if (base + 1 < N) v1 = rp[base + 1];
        if (base + 2 < N) v2 = rp[base + 2];
    }
    int s = v0 + v1 + v2 + v3;
    int lane = t & 63, w = t >> 6;
    int x = s;
    for (int o = 1; o < 64; o <<= 1) {
        int y = __shfl_up(x, o, 64);
        if (lane >= o) x += y;
    }
    __shared__ int wsum[4];
    if (lane == 63) wsum[w] = x;
    __syncthreads();
    int woff = 0;
    for (int i = 0; i < w; ++i) woff += wsum[i];
    int excl = woff + x - s;
    if (base < N) rp[base] = excl;
    if (base + 1 < N) rp[base + 1] = excl + v0;
    if (base + 2 < N) rp[base + 2] = excl + v0 + v1;
    if (base + 3 < N) rp[base + 3] = excl + v0 + v1 + v2;
    if (t == 255) bsum[blockIdx.x] = wsum[0] + wsum[1] + wsum[2] + wsum[3];
}

__global__ void k_scan2(int* bsum, int nb) {
    int t = threadIdx.x;
    int s = (t < nb) ? bsum[t] : 0;
    int lane = t & 63, w = t >> 6;
    int x = s;
    for (int o = 1; o < 64; o <<= 1) {
        int y = __shfl_up(x, o, 64);
        if (lane >= o) x += y;
    }
    __shared__ int wsum[4];
    if (lane == 63) wsum[w] = x;
    __syncthreads();
    int woff = 0;
    for (int i = 0; i < w; ++i) woff += wsum[i];
    if (t < nb) bsum[t] = woff + x - s;
}

__global__ void k_scan3(int* __restrict__ rp, const int* __restrict__ bsum, int N) {
    int i = blockIdx.x * 256 + threadIdx.x;
    if (i < N) rp[i] += bsum[i >> 10];
}

// fill with packed (src, norm); afterwards rp[n] = end(n), start(n) = rp[n-1]
__global__ void k_fill(const int* __restrict__ src, const int* __restrict__ tgt,
                       int* __restrict__ rp, const float* __restrict__ dinv,
                       int2* __restrict__ est, int E) {
    int e = blockIdx.x * 256 + threadIdx.x;
    if (e < E) {
        int t = tgt[e];
        int s = src[e];
        int p = atomicAdd(&rp[t], 1);
        est[p] = make_int2(s, __float_as_int(dinv[s] * dinv[t]));
    }
}

// ---------------- GEMM: out[64 rows of X] <- A(from two half-buffers) @ Wp^T (+cvec) ----------------
__global__ __launch_bounds__(256, 3) void k_gemm(const u16* __restrict__ p0, int rs0,
                                                 const u16* __restrict__ p1, int rs1,
                                                 const u16* __restrict__ W,
                                                 const float* __restrict__ cvec,
                                                 u16* __restrict__ out, int N) {
    __shared__ u16 As[64][260];
    __shared__ u16 Ws[256][36];
    int r0 = blockIdx.x * 64;
    int tid = threadIdx.x, lane = tid & 63, w = tid >> 6;
#pragma unroll
    for (int i = 0; i < 8; ++i) {
        int chunk = i * 256 + tid;
        int r = chunk >> 5, c8 = chunk & 31;
        const u16* sp = (c8 < 16) ? &p0[(size_t)(r0 + r) * rs0 + c8 * 8]
                                  : &p1[(size_t)(r0 + r) * rs1 + (c8 - 16) * 8];
        *(short8*)&As[r][c8 * 8] = *(const short8*)sp;
    }
    f32x4 acc[16];
#pragma unroll
    for (int o = 0; o < 16; ++o) acc[o] = f32x4{0.f, 0.f, 0.f, 0.f};
    for (int k0 = 0; k0 < 256; k0 += 32) {
        __syncthreads();
#pragma unroll
        for (int i = 0; i < 4; ++i) {
            int chunk = i * 256 + tid;
            int r = chunk >> 2, c8 = chunk & 3;
            *(short8*)&Ws[r][c8 * 8] = *(const short8*)&W[(size_t)r * 256 + k0 + c8 * 8];
        }
        __syncthreads();
        half8 af = *(const half8*)&As[w * 16 + (lane & 15)][k0 + (lane >> 4) * 8];
#pragma unroll
        for (int o = 0; o < 16; ++o) {
            half8 wf = *(const half8*)&Ws[o * 16 + (lane & 15)][(lane >> 4) * 8];
            acc[o] = __builtin_amdgcn_mfma_f32_16x16x32_f16(af, wf, acc[o], 0, 0, 0);
        }
    }
    __syncthreads();
#pragma unroll
    for (int o = 0; o < 16; ++o) {
        int col = o * 16 + (lane & 15);
        float cv = cvec ? cvec[col] : 0.f;
#pragma unroll
        for (int r = 0; r < 4; ++r) {
            int row = w * 16 + (lane >> 4) * 4 + r;
            As[row][col] = f2h(acc[o][r] + cv);
        }
    }
    __syncthreads();
#pragma unroll
    for (int i = 0; i < 8; ++i) {
        int chunk = i * 256 + tid;
        int r = chunk >> 5, c8 = chunk & 31;
        *(short8*)&out[(size_t)(r0 + r) * 256 + c8 * 8] = *(const short8*)&As[r][c8 * 8];
    }
}

// ---------------- half aggregation: 16-lane sub-waves, 4-node chunks, edge-parallel ----------------
// Chunk's edges are contiguous [r0, r4); iterate with unroll-4 INDEPENDENT gathers and
// route each edge to its node accumulator via predicated masks (static indexing only).
template <bool RS>
__global__ __launch_bounds__(256) void k_aggh(const u16* __restrict__ src, int srs,
                                              u16* __restrict__ dst, int drs,
                                              const int* __restrict__ rp,
                                              const int2* __restrict__ est,
                                              const float* __restrict__ dinv,
                                              const float* __restrict__ biasH,
                                              float* __restrict__ statS,
                                              float* __restrict__ statQ, int N) {
    int l = threadIdx.x & 15;
    int sub = blockIdx.x * 16 + (threadIdx.x >> 4);
    int n0 = sub * 4;
    float bv[8];
#pragma unroll
    for (int k = 0; k < 8; ++k) bv[k] = biasH[l * 8 + k];
    float ss[8] = {}, qq[8] = {};
    if (n0 < N) {  // N % 4 == 0 -> full chunks
        int r0 = n0 ? rp[n0 - 1] : 0;
        int r1 = rp[n0], r2 = rp[n0 + 1], r3 = rp[n0 + 2], r4 = rp[n0 + 3];
        float d0 = dinv[n0], d1 = dinv[n0 + 1], d2 = dinv[n0 + 2], d3 = dinv[n0 + 3];
        short8 h0 = *(const short8*)&src[(size_t)n0 * srs + l * 8];
        short8 h1 = *(const short8*)&src[(size_t)(n0 + 1) * srs + l * 8];
        short8 h2 = *(const short8*)&src[(size_t)(n0 + 2) * srs + l * 8];
        short8 h3 = *(const short8*)&src[(size_t)(n0 + 3) * srs + l * 8];
        float a0[8], a1[8], a2[8], a3[8];
#pragma unroll
        for (int k = 0; k < 8; ++k) {
            a0[k] = h2f((u16)h0[k]) * d0 * d0 + bv[k];
            a1[k] = h2f((u16)h1[k]) * d1 * d1 + bv[k];
            a2[k] = h2f((u16)h2[k]) * d2 * d2 + bv[k];
            a3[k] = h2f((u16)h3[k]) * d3 * d3 + bv[k];
        }
        for (int j = r0; j < r4; j += 4) {
#pragma unroll
            for (int u = 0; u < 4; ++u) {
                int jj = j + u;
                bool valid = jj < r4;
                int2 e = est[valid ? jj : r0];
                float nr = valid ? __int_as_float(e.y) : 0.f;
                short8 v = *(const short8*)&src[(size_t)e.x * srs + l * 8];
                float m0 = (jj < r1) ? nr : 0.f;
                float m1 = (jj >= r1 && jj < r2) ? nr : 0.f;
                float m2 = (jj >= r2 && jj < r3) ? nr : 0.f;
                float m3 = (jj >= r3) ? nr : 0.f;
#pragma unroll
                for (int k = 0; k < 8; ++k) {
                    float f = h2f((u16)v[k]);
                    a0[k] += f * m0;
                    a1[k] += f * m1;
                    a2[k] += f * m2;
                    a3[k] += f * m3;
                }
            }
        }
        short8 o0, o1, o2, o3;
#pragma unroll
        for (int k = 0; k < 8; ++k) {
            if (RS) {
                a0[k] = fmaxf(a0[k], 0.f); a1[k] = fmaxf(a1[k], 0.f);
                a2[k] = fmaxf(a2[k], 0.f); a3[k] = fmaxf(a3[k], 0.f);
                ss[k] += a0[k] + a1[k] + a2[k] + a3[k];
                qq[k] += a0[k] * a0[k] + a1[k] * a1[k] + a2[k] * a2[k] + a3[k] * a3[k];
            }
            o0[k] = (short)f2h(a0[k]); o1[k] = (short)f2h(a1[k]);
            o2[k] = (short)f2h(a2[k]); o3[k] = (short)f2h(a3[k]);
        }
        *(short8*)&dst[(size_t)n0 * drs + l * 8] = o0;
        *(short8*)&dst[(size_t)(n0 + 1) * drs + l * 8] = o1;
        *(short8*)&dst[(size_t)(n0 + 2) * drs + l * 8] = o2;
        *(short8*)&dst[(size_t)(n0 + 3) * drs + l * 8] = o3;
    }
    if (RS) {
        __shared__ float sh[256];
        int t = threadIdx.x;
        sh[t] = 0.f;
        __syncthreads();
#pragma unroll
        for (int k = 0; k < 8; ++k) {
            atomicAdd(&sh[l * 8 + k], ss[k]);
            atomicAdd(&sh[128 + l * 8 + k], qq[k]);
        }
        __syncthreads();
        if (t < 128)
            atomicAdd(&statS[t], sh[t]);
        else
            atomicAdd(&statQ[t - 128], sh[t]);
    }
}

// ---------------- half snapshot copy (fallback tier) ----------------
__global__ void k_copyh(const u16* __restrict__ src, u16* __restrict__ dst, int N) {
    int i = blockIdx.x * 256 + threadIdx.x;
    if (i >= N * 16) return;
    int n = i >> 4, c8 = (i & 15) * 8;
    *(short8*)&dst[(size_t)n * 128 + c8] = *(const short8*)&src[(size_t)n * 256 + c8];
}

__global__ void k_bnparam(const float* __restrict__ stats, const float* __restrict__ gamma,
                          const float* __restrict__ beta, float* __restrict__ st, int N) {
    int d = threadIdx.x;
    float inv = 1.f / (float)N;
    float mu = stats[d] * inv;
    float var = fmaxf(stats[256 + d] * inv - mu * mu, 0.f);
    float sc = gamma[d] * rsqrtf(var + 1e-5f);
    st[d] = sc;
    st[256 + d] = beta[d] - mu * sc;
}

__global__ void k_fold(const float* __restrict__ W, const float* __restrict__ st,
                       u16* __restrict__ Wp, float* __restrict__ cvec) {
    __shared__ float red[256];
    int o = blockIdx.x, k = threadIdx.x;
    float w = W[o * 256 + k];
    Wp[o * 256 + k] = f2h(w * st[k]);
    red[k] = w * st[256 + k];
    __syncthreads();
    for (int s = 128; s > 0; s >>= 1) {
        if (k < s) red[k] += red[k + s];
        __syncthreads();
    }
    if (k == 0) cvec[o] = red[0];
}

// ---------------- set2set GEMM: C[M,O](f16) = A[M,K](f16) @ W[O,K](f16)^T + cvec ----------------
__global__ __launch_bounds__(256, 2) void k_gemmf(const u16* __restrict__ A,
                                                  const u16* __restrict__ W,
                                                  const float* __restrict__ cvec,
                                                  u16* __restrict__ C, int M, int K, int O) {
    const int PAD = 8;
    __shared__ u16 As[128][64 + PAD];
    __shared__ u16 Ws[128][64 + PAD];
    int tM = blockIdx.x, tO = blockIdx.y;
    int tid = threadIdx.x;
    int lane = tid & 63, wid = tid >> 6;
    int wM = wid & 1, wO = wid >> 1;
    f32x4 acc[4][4] = {};
    size_t rowA0 = (size_t)tM * 128, rowW0 = (size_t)tO * 128;
    for (int k0 = 0; k0 < K; k0 += 64) {
#pragma unroll
        for (int i = 0; i < 4; ++i) {
            int chunk = tid + i * 256;
            int r = chunk >> 3, c16 = chunk & 7;
            *(short8*)&As[r][c16 * 8] = *(const short8*)&A[(rowA0 + r) * K + k0 + c16 * 8];
            *(short8*)&Ws[r][c16 * 8] = *(const short8*)&W[(rowW0 + r) * K + k0 + c16 * 8];
        }
        __syncthreads();
#pragma unroll
        for (int ks = 0; ks < 2; ++ks) {
            half8 af[4], wf[4];
#pragma unroll
            for (int m = 0; m < 4; ++m)
                af[m] = *(const half8*)&As[wM * 64 + m * 16 + (lane & 15)][ks * 32 + (lane >> 4) * 8];
#pragma unroll
            for (int o = 0; o < 4; ++o)
                wf[o] = *(const half8*)&Ws[wO * 64 + o * 16 + (lane & 15)][ks * 32 + (lane >> 4) * 8];
#pragma unroll
            for (int m = 0; m < 4; ++m)
#pragma unroll
                for (int o = 0; o < 4; ++o)
                    acc[m][o] = __builtin_amdgcn_mfma_f32_16x16x32_f16(af[m], wf[o], acc[m][o], 0, 0, 0);
        }
        __syncthreads();
    }
#pragma unroll
    for (int m = 0; m < 4; ++m) {
        int R0 = tM * 128 + wM * 64 + m * 16 + (lane >> 4) * 4;
#pragma unroll
        for (int o = 0; o < 4; ++o) {
            int Cc = tO * 128 + wO * 64 + o * 16 + (lane & 15);
            float cv = cvec[Cc];
#pragma unroll
            for (int r = 0; r < 4; ++r)
                C[(size_t)(R0 + r) * O + Cc] = f2h(acc[m][o][r] + cv);
        }
    }
}

// ---------------- set2set pieces ----------------
__global__ void k_wcat(const float* __restrict__ Wi, const float* __restrict__ Wh,
                       const float* __restrict__ bi, const float* __restrict__ bh,
                       u16* __restrict__ Wcat, float* __restrict__ bcat) {
    int o = blockIdx.x;
    int t = threadIdx.x;
    for (int c = t; c < 512; c += 256) Wcat[(size_t)o * 768 + c] = f2h(Wi[(size_t)o * 512 + c]);
    if (t < 256) Wcat[(size_t)o * 768 + 512 + t] = f2h(Wh[(size_t)o * 256 + t]);
    if (t == 0) bcat[o] = bi[o] + bh[o];
}

__global__ void k_lstm(const u16* __restrict__ gates, float* __restrict__ cs,
                       float* __restrict__ hsb, u16* __restrict__ qsh, int G) {
    int idx = blockIdx.x * 256 + threadIdx.x;
    if (idx >= G * 256) return;
    int g = idx >> 8, d = idx & 255;
    const u16* gt = &gates[(size_t)g * 1024];
    float gi = h2f(gt[d]), gf = h2f(gt[256 + d]), gg = h2f(gt[512 + d]), go = h2f(gt[768 + d]);
    float c = sigf(gf) * cs[idx] + sigf(gi) * tanhf(gg);
    float hh = sigf(go) * tanhf(c);
    cs[idx] = c;
    hsb[idx] = hh;
    u16 hb = f2h(hh);
    qsh[(size_t)g * 768 + d] = hb;
    qsh[(size_t)g * 768 + 512 + d] = hb;
}

// ---------------- attention: one wave per graph; h3 may be split across two buffers ----------------
__global__ __launch_bounds__(256) void k_attn2(const u16* __restrict__ lo, int lstr,
                                               const u16* __restrict__ hi, int hstr,
                                               const float* __restrict__ hs,
                                               const int* __restrict__ gstart,
                                               u16* __restrict__ qsh, int G) {
    int wid = threadIdx.x >> 6, lane = threadIdx.x & 63;
    int g = blockIdx.x * 4 + wid;
    if (g >= G) return;
    int start = gstart[g], end = gstart[g + 1];

    const u16* base = (lane < 32) ? lo : hi;
    size_t stride = (lane < 32) ? lstr : hstr;
    int coff = (lane < 32) ? lane * 4 : (lane - 32) * 4;

    f32x4 q = *(const f32x4*)&hs[(size_t)g * 256 + lane * 4];
    float m = -INFINITY, z = 0.f;
    float r0a = 0.f, r1a = 0.f, r2a = 0.f, r3a = 0.f;

    for (int c0 = start; c0 < end; c0 += 256) {
        int cn = min(256, end - c0);
        float e0 = 0.f, e1 = 0.f, e2 = 0.f, e3 = 0.f;
        float mc = m;

        auto pass1 = [&](int rr, float& ev) {
            int b = c0 + rr * 64;
            int nr = min(64, end - b);
            for (int ii = 0; ii < nr; ++ii) {
                u16x4 hv = *(const u16x4*)&base[(size_t)(b + ii) * stride + coff];
                float e = h2f(hv[0]) * q[0] + h2f(hv[1]) * q[1] + h2f(hv[2]) * q[2] + h2f(hv[3]) * q[3];
                e += __shfl_xor(e, 32, 64);
                e += __shfl_xor(e, 16, 64);
                e += __shfl_xor(e, 8, 64);
                e += __shfl_xor(e, 4, 64);
                e += __shfl_xor(e, 2, 64);
                e += __shfl_xor(e, 1, 64);
                if (lane == ii) ev = e;
                mc = fmaxf(mc, e);
            }
        };
        pass1(0, e0);
        pass1(1, e1);
        pass1(2, e2);
        pass1(3, e3);

        float rf = (m == -INFINITY) ? 0.f : expf(m - mc);
        float zc = 0.f;
        e0 = (lane < cn) ? expf(e0 - mc) : 0.f;
        zc += e0;
        e1 = (64 + lane < cn) ? expf(e1 - mc) : 0.f;
        zc += e1;
        e2 = (128 + lane < cn) ? expf(e2 - mc) : 0.f;
        zc += e2;
        e3 = (192 + lane < cn) ? expf(e3 - mc) : 0.f;
        zc += e3;
        zc += __shfl_xor(zc, 32, 64);
        zc += __shfl_xor(zc, 16, 64);
        zc += __shfl_xor(zc, 8, 64);
        zc += __shfl_xor(zc, 4, 64);
        zc += __shfl_xor(zc, 2, 64);
        zc += __shfl_xor(zc, 1, 64);
        z = z * rf + zc;
        r0a *= rf; r1a *= rf; r2a *= rf; r3a *= rf;

        auto pass2 = [&](int rr, float ev) {
            int b = c0 + rr * 64;
            int nr = min(64, end - b);
            for (int ii = 0; ii < nr; ++ii) {
                float w = __shfl(ev, ii, 64);
                u16x4 hv = *(const u16x4*)&base[(size_t)(b + ii) * stride + coff];
                r0a += w * h2f(hv[0]);
                r1a += w * h2f(hv[1]);
                r2a += w * h2f(hv[2]);
                r3a += w * h2f(hv[3]);
            }
        };
        pass2(0, e0);
        pass2(1, e1);
        pass2(2, e2);
        pass2(3, e3);
        m = mc;
    }
    float inv = (end > start) ? 1.f / fmaxf(z, 1e-30f) : 0.f;
    u16x4 o;
    o[0] = f2h(r0a * inv);
    o[1] = f2h(r1a * inv);
    o[2] = f2h(r2a * inv);
    o[3] = f2h(r3a * inv);
    int qcol = (lane < 32) ? lane * 4 : 128 + (lane - 32) * 4;
    *(u16x4*)&qsh[(size_t)g * 768 + 256 + qcol] = o;
}

// lin1/lin2 compose
__global__ void k_wfold(const float* __restrict__ l1W, const float* __restrict__ l1b,
                        const float* __restrict__ l2W, const float* __restrict__ l2b,
                        float* __restrict__ weff) {
    int c = blockIdx.x * 256 + threadIdx.x;
    if (c < 512) {
        float s = 0.f;
        for (int t = 0; t < 128; ++t) s += l2W[t] * l1W[(size_t)t * 512 + c];
        weff[c] = s;
    }
    if (c == 0) {
        float b = l2b[0];
        for (int t = 0; t < 128; ++t) b += l2W[t] * l1b[t];
        weff[512] = b;
    }
}

__global__ __launch_bounds__(256) void k_final2(const u16* __restrict__ qsh,
                                                const float* __restrict__ weff,
                                                float* __restrict__ out, int G) {
    __shared__ float wsm[513];
    int tid = threadIdx.x;
    for (int j = tid; j < 513; j += 256) wsm[j] = weff[j];
    __syncthreads();
    int g = blockIdx.x * 4 + (tid >> 6);
    int lane = tid & 63;
    if (g >= G) return;
    const u16* qp = &qsh[(size_t)g * 768];
    float s = 0.f;
#pragma unroll
    for (int j = 0; j < 8; ++j) s += h2f(qp[lane * 8 + j]) * wsm[lane * 8 + j];
    for (int off = 32; off; off >>= 1) s += __shfl_xor(s, off, 64);
    if (lane == 0) out[g] = sigf(s + wsm[512]);
}

// ---------------- host ----------------
extern "C" void kernel_launch(void* const* d_in, const int* in_sizes, int n_in,
                              void* d_out, int out_size, void* d_ws, size_t ws_size,
                              hipStream_t stream) {
    const int* x = (const int*)d_in[0];
    const int* ei = (const int*)d_in[1];
    const int* batch = (const int*)d_in[2];
    const float* atom_emb = (const float*)d_in[4];
    const float* W1 = (const float*)d_in[5];
    const float* b1 = (const float*)d_in[6];
    const float* W2 = (const float*)d_in[7];
    const float* b2 = (const float*)d_in[8];
    const float* W3 = (const float*)d_in[9];
    const float* b3 = (const float*)d_in[10];
    const float* gamma = (const float*)d_in[11];
    const float* beta = (const float*)d_in[12];
    const float* Wi = (const float*)d_in[13];
    const float* Wh = (const float*)d_in[14];
    const float* bi = (const float*)d_in[15];
    const float* bh = (const float*)d_in[16];
    const float* l1W = (const float*)d_in[17];
    const float* l1b = (const float*)d_in[18];
    const float* l2W = (const float*)d_in[19];
    const float* l2b = (const float*)d_in[20];

    const int N = in_sizes[0] / 9;
    const int E = in_sizes[1] / 2;
    const int G = out_size;
    const int* srcp = ei;
    const int* tgtp = ei + E;

    char* ws = (char*)d_ws;
    size_t off = 0;
    auto alloc = [&](size_t bytes) -> void* {
        void* p = ws + off;
        off += (bytes + 255) & ~(size_t)255;
        return p;
    };
    u16* X = (u16*)alloc((size_t)N * 256 * 2);  // 128 MiB
    int* rp = (int*)alloc((size_t)N * 4);
    int2* est = (int2*)alloc((size_t)E * 8);
    float* dinv = (float*)alloc((size_t)N * 4);
    int* gstart = (int*)alloc((size_t)(G + 1) * 4);
    float* stats = (float*)alloc(512 * 4);
    float* stbuf = (float*)alloc(512 * 4);
    float* cvec = (float*)alloc(256 * 4);
    u16* Wp = (u16*)alloc(256 * 256 * 2);
    int* bsum = (int*)alloc(1024 * 4);
    float* weff = (float*)alloc(513 * 4);
    size_t offR = off;

    size_t halfB = ((size_t)N * 128 * 2 + 255) & ~(size_t)255;  // 64 MiB
    size_t s2sR = 0;
    {
        size_t t = 0;
        auto sz = [&](size_t b) { t += (b + 255) & ~(size_t)255; };
        sz((size_t)1024 * 768 * 2);  // Wcat
        sz(1024 * 4);                // bcat
        sz((size_t)G * 768 * 2);     // qsh
        sz((size_t)G * 1024 * 2);    // gates
        sz((size_t)G * 256 * 4);     // hsb
        sz((size_t)G * 256 * 4);     // csb
        s2sR = t;
    }
    size_t needA = offR + halfB + s2sR;                   // Y live through s2s
    size_t needB = offR + (halfB > s2sR ? halfB : s2sR);  // s2s aliases Y
    bool tierA = ws_size >= needA;
    if (!tierA && ws_size < needB) {
        k_diagf<<<(G + 255) / 256, 256, 0, stream>>>((float*)d_out, G, 12345.0f);
        return;
    }
    u16* Y = (u16*)(ws + offR);
    size_t s2sBase = tierA ? offR + halfB : offR;
    size_t o2 = s2sBase;
    auto alloc2 = [&](size_t bytes) -> void* {
        void* p = ws + o2;
        o2 += (bytes + 255) & ~(size_t)255;
        return p;
    };
    u16* Wcat = (u16*)alloc2((size_t)1024 * 768 * 2);
    float* bcat = (float*)alloc2(1024 * 4);
    u16* qsh = (u16*)alloc2((size_t)G * 768 * 2);
    u16* gates = (u16*)alloc2((size_t)G * 1024 * 2);
    float* hsb = (float*)alloc2((size_t)G * 256 * 4);
    float* csb = (float*)alloc2((size_t)G * 256 * 4);

    // embed + segment starts + CSR
    k_embed<<<N / 8, 256, 0, stream>>>(x, atom_emb, X, N);
    k_gstart<<<(N + 255) / 256, 256, 0, stream>>>(batch, gstart, N, G);
    k_zero_int<<<(N + 255) / 256, 256, 0, stream>>>(rp, N);
    k_count<<<(E + 255) / 256, 256, 0, stream>>>(tgtp, rp, E);
    k_dinv<<<(N + 255) / 256, 256, 0, stream>>>(rp, dinv, N);
    int nb1 = (N + 1023) / 1024;
    k_scan1<<<nb1, 256, 0, stream>>>(rp, bsum, N);
    k_scan2<<<1, 256, 0, stream>>>(bsum, nb1);
    k_scan3<<<(N + 255) / 256, 256, 0, stream>>>(rp, bsum, N);
    k_fill<<<(E + 255) / 256, 256, 0, stream>>>(srcp, tgtp, rp, dinv, est, E);

    int gipb = N / 64;
    int cpb = (N * 16 + 255) / 256;
    int aggb = (N / 4 + 15) / 16;

    // conv1: GEMM X->X; agg h0: X+0 -> Y; agg h1: X+128 -> X+0. State: (Y/128, X+0/256).
    k_cvtW<<<256, 256, 0, stream>>>(W1, Wp, 65536);
    k_zero_f32<<<2, 256, 0, stream>>>(stats, 512);
    k_gemm<<<gipb, 256, 0, stream>>>(X, 256, X + 128, 256, Wp, nullptr, X, N);
    k_aggh<true><<<aggb, 256, 0, stream>>>(X, 256, Y, 128, rp, est, dinv, b1, stats, stats + 256, N);
    k_aggh<true><<<aggb, 256, 0, stream>>>(X + 128, 256, X, 256, rp, est, dinv, b1 + 128, stats + 128, stats + 384, N);
    k_bnparam<<<1, 256, 0, stream>>>(stats, gamma, beta, stbuf, N);

    // conv2
    k_fold<<<256, 256, 0, stream>>>(W2, stbuf, Wp, cvec);
    k_zero_f32<<<2, 256, 0, stream>>>(stats, 512);
    k_gemm<<<gipb, 256, 0, stream>>>(Y, 128, X, 256, Wp, cvec, X, N);
    k_aggh<true><<<aggb, 256, 0, stream>>>(X, 256, Y, 128, rp, est, dinv, b2, stats, stats + 256, N);
    k_aggh<true><<<aggb, 256, 0, stream>>>(X + 128, 256, X, 256, rp, est, dinv, b2 + 128, stats + 128, stats + 384, N);
    k_bnparam<<<1, 256, 0, stream>>>(stats, gamma, beta, stbuf, N);

    // conv3
    k_fold<<<256, 256, 0, stream>>>(W3, stbuf, Wp, cvec);
    k_gemm<<<gipb, 256, 0, stream>>>(Y, 128, X, 256, Wp, cvec, X, N);
    const u16 *h3lo, *h3hi;
    int h3ls, h3hs;
    if (tierA) {
        k_aggh<false><<<aggb, 256, 0, stream>>>(X, 256, Y, 128, rp, est, dinv, b3, nullptr, nullptr, N);
        k_aggh<false><<<aggb, 256, 0, stream>>>(X + 128, 256, X, 256, rp, est, dinv, b3 + 128, nullptr, nullptr, N);
        h3lo = Y; h3ls = 128; h3hi = X; h3hs = 256;
    } else {
        k_copyh<<<cpb, 256, 0, stream>>>(X, Y, N);
        k_aggh<false><<<aggb, 256, 0, stream>>>(Y, 128, X, 256, rp, est, dinv, b3, nullptr, nullptr, N);
        k_copyh<<<cpb, 256, 0, stream>>>(X + 128, Y, N);
        k_aggh<false><<<aggb, 256, 0, stream>>>(Y, 128, X + 128, 256, rp, est, dinv, b3 + 128, nullptr, nullptr, N);
        h3lo = X; h3ls = 256; h3hi = X + 128; h3hs = 256;
    }

    // set2set
    k_wcat<<<1024, 256, 0, stream>>>(Wi, Wh, bi, bh, Wcat, bcat);
    k_zero_u16<<<(G * 768 + 255) / 256, 256, 0, stream>>>(qsh, G * 768);
    k_zero_f32<<<(G * 256 + 255) / 256, 256, 0, stream>>>(csb, G * 256);
    dim3 ggates(G / 128, 8);
    for (int s = 0; s < 4; ++s) {
        k_gemmf<<<ggates, 256, 0, stream>>>(qsh, Wcat, bcat, gates, G, 768, 1024);
        k_lstm<<<(G * 256 + 255) / 256, 256, 0, stream>>>(gates, csb, hsb, qsh, G);
        k_attn2<<<(G + 3) / 4, 256, 0, stream>>>(h3lo, h3ls, h3hi, h3hs, hsb, gstart, qsh, G);
    }
    k_wfold<<<2, 256, 0, stream>>>(l1W, l1b, l2W, l2b, weff);
    k_final2<<<(G + 3) / 4, 256, 0, stream>>>(qsh, weff, (float*)d_out, G);
}

// Round 14
// 1472.114 us; speedup vs baseline: 1.0097x; 1.0097x over previous
//
#include <hip/hip_runtime.h>
#include <hip/hip_bf16.h>
#include <math.h>

using u16 = unsigned short;
typedef __attribute__((ext_vector_type(8))) short short8;
typedef __attribute__((ext_vector_type(8))) _Float16 half8;
typedef __attribute__((ext_vector_type(4))) float f32x4;
typedef __attribute__((ext_vector_type(4))) u16 u16x4;

__device__ __constant__ int c_OFF[9] = {0, 119, 123, 135, 147, 157, 163, 169, 171};

__device__ __forceinline__ float h2f(u16 u) {
    _Float16 h;
    __builtin_memcpy(&h, &u, 2);
    return (float)h;
}
__device__ __forceinline__ u16 f2h(float f) {
    _Float16 h = (_Float16)f;
    u16 u;
    __builtin_memcpy(&u, &h, 2);
    return u;
}
__device__ __forceinline__ float sigf(float x) { return 1.f / (1.f + expf(-x)); }

// ---------------- diagnostics ----------------
__global__ void k_diagf(float* out, int G, float val) {
    int i = blockIdx.x * 256 + threadIdx.x;
    if (i < G) out[i] = val;
}

// ---------------- zero helpers ----------------
__global__ void k_zero_f32(float* p, int n) {
    int i = blockIdx.x * 256 + threadIdx.x;
    if (i < n) p[i] = 0.f;
}
__global__ void k_zero_u16(u16* p, int n) {
    int i = blockIdx.x * 256 + threadIdx.x;
    if (i < n) p[i] = 0;
}
__global__ void k_zero_int(int* p, int n) {
    int i = blockIdx.x * 256 + threadIdx.x;
    if (i < n) p[i] = 0;
}

// ---------------- fp32 -> fp16 convert ----------------
__global__ void k_cvtW(const float* __restrict__ src, u16* __restrict__ dst, int n) {
    int i = blockIdx.x * 256 + threadIdx.x;
    if (i < n) dst[i] = f2h(src[i]);
}

// ---------------- atom encoder: 8 nodes/block, 8 cols/thread, vectorized ----------------
__global__ __launch_bounds__(256) void k_embed(const int* __restrict__ x,
                                               const float* __restrict__ emb,
                                               u16* __restrict__ out, int N) {
    __shared__ int rows[72];
    int nb = blockIdx.x * 8;
    int tid = threadIdx.x;
    if (tid < 72) rows[tid] = x[(size_t)nb * 9 + tid] + c_OFF[tid % 9];
    __syncthreads();
    int ln = tid >> 5;
    int c8 = (tid & 31) * 8;
    float s0 = 0.f, s1 = 0.f, s2 = 0.f, s3 = 0.f, s4 = 0.f, s5 = 0.f, s6 = 0.f, s7 = 0.f;
#pragma unroll
    for (int c = 0; c < 9; ++c) {
        int r = rows[ln * 9 + c];
        f32x4 a = *(const f32x4*)&emb[r * 256 + c8];
        f32x4 b = *(const f32x4*)&emb[r * 256 + c8 + 4];
        s0 += a[0]; s1 += a[1]; s2 += a[2]; s3 += a[3];
        s4 += b[0]; s5 += b[1]; s6 += b[2]; s7 += b[3];
    }
    short8 o;
    o[0] = (short)f2h(s0); o[1] = (short)f2h(s1); o[2] = (short)f2h(s2); o[3] = (short)f2h(s3);
    o[4] = (short)f2h(s4); o[5] = (short)f2h(s5); o[6] = (short)f2h(s6); o[7] = (short)f2h(s7);
    *(short8*)&out[(size_t)(nb + ln) * 256 + c8] = o;
}

// ---------------- graph segment starts from sorted batch ----------------
__global__ void k_gstart(const int* __restrict__ batch, int* __restrict__ gstart, int N, int G) {
    int i = blockIdx.x * 256 + threadIdx.x;
    if (i >= N) return;
    int b = batch[i];
    if (i == 0) {
        for (int g = 0; g <= b; ++g) gstart[g] = 0;
    } else {
        int p = batch[i - 1];
        for (int g = p + 1; g <= b; ++g) gstart[g] = i;
    }
    if (i == N - 1) {
        for (int g = b + 1; g <= G; ++g) gstart[g] = N;
    }
}

// ---------------- CSR build (in-place in rp) ----------------
__global__ void k_count(const int* __restrict__ tgt, int* rp, int E) {
    int e = blockIdx.x * 256 + threadIdx.x;
    if (e < E) atomicAdd(&rp[tgt[e]], 1);
}

__global__ void k_dinv(const int* __restrict__ cnt, float* __restrict__ dinv, int N) {
    int i = blockIdx.x * 256 + threadIdx.x;
    if (i < N) dinv[i] = rsqrtf((float)cnt[i] + 1.f);
}

__global__ void k_scan1(int* __restrict__ rp, int* __restrict__ bsum, int N) {
    int t = threadIdx.x;
    int base = blockIdx.x * 1024 + t * 4;
    int v0 = 0, v1 = 0, v2 = 0, v3 = 0;
    if (base + 3 < N) {
        v0 = rp[base]; v1 = rp[base + 1]; v2 = rp[base + 2]; v3 = rp[base + 3];
    } else {
        if (base < N) v0 = rp[base];
        if (base + 1 < N) v1 = rp[base + 1];
        if (base + 2 < N) v2 = rp[base + 2];
    }
    int s = v0 + v1 + v2 + v3;
    int lane = t & 63, w = t >> 6;
    int x = s;
    for (int o = 1; o < 64; o <<= 1) {
        int y = __shfl_up(x, o, 64);
        if (lane >= o) x += y;
    }
    __shared__ int wsum[4];
    if (lane == 63) wsum[w] = x;
    __syncthreads();
    int woff = 0;
    for (int i = 0; i < w; ++i) woff += wsum[i];
    int excl = woff + x - s;
    if (base < N) rp[base] = excl;
    if (base + 1 < N) rp[base + 1] = excl + v0;
    if (base + 2 < N) rp[base + 2] = excl + v0 + v1;
    if (base + 3 < N) rp[base + 3] = excl + v0 + v1 + v2;
    if (t == 255) bsum[blockIdx.x] = wsum[0] + wsum[1] + wsum[2] + wsum[3];
}

__global__ void k_scan2(int* bsum, int nb) {
    int t = threadIdx.x;
    int s = (t < nb) ? bsum[t] : 0;
    int lane = t & 63, w = t >> 6;
    int x = s;
    for (int o = 1; o < 64; o <<= 1) {
        int y = __shfl_up(x, o, 64);
        if (lane >= o) x += y;
    }
    __shared__ int wsum[4];
    if (lane == 63) wsum[w] = x;
    __syncthreads();
    int woff = 0;
    for (int i = 0; i < w; ++i) woff += wsum[i];
    if (t < nb) bsum[t] = woff + x - s;
}

__global__ void k_scan3(int* __restrict__ rp, const int* __restrict__ bsum, int N) {
    int i = blockIdx.x * 256 + threadIdx.x;
    if (i < N) rp[i] += bsum[i >> 10];
}

// fill with packed (src, norm); afterwards rp[n] = end(n), start(n) = rp[n-1]
__global__ void k_fill(const int* __restrict__ src, const int* __restrict__ tgt,
                       int* __restrict__ rp, const float* __restrict__ dinv,
                       int2* __restrict__ est, int E) {
    int e = blockIdx.x * 256 + threadIdx.x;
    if (e < E) {
        int t = tgt[e];
        int s = src[e];
        int p = atomicAdd(&rp[t], 1);
        est[p] = make_int2(s, __float_as_int(dinv[s] * dinv[t]));
    }
}

// ---------------- GEMM: out[64 rows of X] <- A(from two half-buffers) @ Wp^T (+cvec) ----------------
__global__ __launch_bounds__(256, 3) void k_gemm(const u16* __restrict__ p0, int rs0,
                                                 const u16* __restrict__ p1, int rs1,
                                                 const u16* __restrict__ W,
                                                 const float* __restrict__ cvec,
                                                 u16* __restrict__ out, int N) {
    __shared__ u16 As[64][260];
    __shared__ u16 Ws[256][36];
    int r0 = blockIdx.x * 64;
    int tid = threadIdx.x, lane = tid & 63, w = tid >> 6;
#pragma unroll
    for (int i = 0; i < 8; ++i) {
        int chunk = i * 256 + tid;
        int r = chunk >> 5, c8 = chunk & 31;
        const u16* sp = (c8 < 16) ? &p0[(size_t)(r0 + r) * rs0 + c8 * 8]
                                  : &p1[(size_t)(r0 + r) * rs1 + (c8 - 16) * 8];
        *(short8*)&As[r][c8 * 8] = *(const short8*)sp;
    }
    f32x4 acc[16];
#pragma unroll
    for (int o = 0; o < 16; ++o) acc[o] = f32x4{0.f, 0.f, 0.f, 0.f};
    for (int k0 = 0; k0 < 256; k0 += 32) {
        __syncthreads();
#pragma unroll
        for (int i = 0; i < 4; ++i) {
            int chunk = i * 256 + tid;
            int r = chunk >> 2, c8 = chunk & 3;
            *(short8*)&Ws[r][c8 * 8] = *(const short8*)&W[(size_t)r * 256 + k0 + c8 * 8];
        }
        __syncthreads();
        half8 af = *(const half8*)&As[w * 16 + (lane & 15)][k0 + (lane >> 4) * 8];
#pragma unroll
        for (int o = 0; o < 16; ++o) {
            half8 wf = *(const half8*)&Ws[o * 16 + (lane & 15)][(lane >> 4) * 8];
            acc[o] = __builtin_amdgcn_mfma_f32_16x16x32_f16(af, wf, acc[o], 0, 0, 0);
        }
    }
    __syncthreads();
#pragma unroll
    for (int o = 0; o < 16; ++o) {
        int col = o * 16 + (lane & 15);
        float cv = cvec ? cvec[col] : 0.f;
#pragma unroll
        for (int r = 0; r < 4; ++r) {
            int row = w * 16 + (lane >> 4) * 4 + r;
            As[row][col] = f2h(acc[o][r] + cv);
        }
    }
    __syncthreads();
#pragma unroll
    for (int i = 0; i < 8; ++i) {
        int chunk = i * 256 + tid;
        int r = chunk >> 5, c8 = chunk & 31;
        *(short8*)&out[(size_t)(r0 + r) * 256 + c8 * 8] = *(const short8*)&As[r][c8 * 8];
    }
}

// ---------------- FULL-width aggregation: 32-lane sub-waves, 4-node chunks ----------------
// Reads full 512B rows of src (stride 256), writes lo half -> dlo (stride 128), hi -> dhi.
template <bool RS>
__global__ __launch_bounds__(256) void k_aggf(const u16* __restrict__ src,
                                              u16* __restrict__ dlo,
                                              u16* __restrict__ dhi,
                                              const int* __restrict__ rp,
                                              const int2* __restrict__ est,
                                              const float* __restrict__ dinv,
                                              const float* __restrict__ bias,
                                              float* __restrict__ stats, int N) {
    int l = threadIdx.x & 31;
    int sub = blockIdx.x * 8 + (threadIdx.x >> 5);
    int n0 = sub * 4;
    float bv[8];
#pragma unroll
    for (int k = 0; k < 8; ++k) bv[k] = bias[l * 8 + k];
    float ss[8] = {}, qq[8] = {};
    if (n0 < N) {
        int rA = n0 ? rp[n0 - 1] : 0;
#pragma unroll
        for (int t = 0; t < 4; ++t) {
            int n = n0 + t;
            int rB = rp[n];
            float dn = dinv[n];
            short8 hv = *(const short8*)&src[(size_t)n * 256 + l * 8];
            float a[8];
#pragma unroll
            for (int k = 0; k < 8; ++k) a[k] = h2f((u16)hv[k]) * dn * dn + bv[k];
            int j = rA;
            for (; j + 1 < rB; j += 2) {
                int2 e0 = est[j], e1 = est[j + 1];
                float n0f = __int_as_float(e0.y), n1f = __int_as_float(e1.y);
                short8 v0 = *(const short8*)&src[(size_t)e0.x * 256 + l * 8];
                short8 v1 = *(const short8*)&src[(size_t)e1.x * 256 + l * 8];
#pragma unroll
                for (int k = 0; k < 8; ++k) a[k] += h2f((u16)v0[k]) * n0f + h2f((u16)v1[k]) * n1f;
            }
            if (j < rB) {
                int2 e0 = est[j];
                float n0f = __int_as_float(e0.y);
                short8 v0 = *(const short8*)&src[(size_t)e0.x * 256 + l * 8];
#pragma unroll
                for (int k = 0; k < 8; ++k) a[k] += h2f((u16)v0[k]) * n0f;
            }
            rA = rB;
            short8 o;
#pragma unroll
            for (int k = 0; k < 8; ++k) {
                if (RS) {
                    a[k] = fmaxf(a[k], 0.f);
                    ss[k] += a[k];
                    qq[k] += a[k] * a[k];
                }
                o[k] = (short)f2h(a[k]);
            }
            if (l < 16)
                *(short8*)&dlo[(size_t)n * 128 + l * 8] = o;
            else
                *(short8*)&dhi[(size_t)n * 128 + (l - 16) * 8] = o;
        }
    }
    if (RS) {
        __shared__ float sh[512];
        int t = threadIdx.x;
        sh[t] = 0.f;
        sh[t + 256] = 0.f;
        __syncthreads();
#pragma unroll
        for (int k = 0; k < 8; ++k) {
            atomicAdd(&sh[l * 8 + k], ss[k]);
            atomicAdd(&sh[256 + l * 8 + k], qq[k]);
        }
        __syncthreads();
        atomicAdd(&stats[t], sh[t]);
        atomicAdd(&stats[t + 256], sh[t + 256]);
    }
}

// ---------------- half aggregation (tier A/B): 16-lane sub-waves, 4-node chunks ----------------
template <bool RS>
__global__ __launch_bounds__(256) void k_aggh(const u16* __restrict__ src, int srs,
                                              u16* __restrict__ dst, int drs,
                                              const int* __restrict__ rp,
                                              const int2* __restrict__ est,
                                              const float* __restrict__ dinv,
                                              const float* __restrict__ biasH,
                                              float* __restrict__ statS,
                                              float* __restrict__ statQ, int N) {
    int l = threadIdx.x & 15;
    int sub = blockIdx.x * 16 + (threadIdx.x >> 4);
    int n0 = sub * 4;
    float bv[8];
#pragma unroll
    for (int k = 0; k < 8; ++k) bv[k] = biasH[l * 8 + k];
    float ss[8] = {}, qq[8] = {};
    if (n0 < N) {
        int rA = n0 ? rp[n0 - 1] : 0;
#pragma unroll
        for (int t = 0; t < 4; ++t) {
            int n = n0 + t;
            int rB = rp[n];
            float dn = dinv[n];
            short8 hv = *(const short8*)&src[(size_t)n * srs + l * 8];
            float a[8];
#pragma unroll
            for (int k = 0; k < 8; ++k) a[k] = h2f((u16)hv[k]) * dn * dn + bv[k];
            int j = rA;
            for (; j + 1 < rB; j += 2) {
                int2 e0 = est[j], e1 = est[j + 1];
                float n0f = __int_as_float(e0.y), n1f = __int_as_float(e1.y);
                short8 v0 = *(const short8*)&src[(size_t)e0.x * srs + l * 8];
                short8 v1 = *(const short8*)&src[(size_t)e1.x * srs + l * 8];
#pragma unroll
                for (int k = 0; k < 8; ++k) a[k] += h2f((u16)v0[k]) * n0f + h2f((u16)v1[k]) * n1f;
            }
            if (j < rB) {
                int2 e0 = est[j];
                float n0f = __int_as_float(e0.y);
                short8 v0 = *(const short8*)&src[(size_t)e0.x * srs + l * 8];
#pragma unroll
                for (int k = 0; k < 8; ++k) a[k] += h2f((u16)v0[k]) * n0f;
            }
            rA = rB;
            short8 o;
#pragma unroll
            for (int k = 0; k < 8; ++k) {
                if (RS) {
                    a[k] = fmaxf(a[k], 0.f);
                    ss[k] += a[k];
                    qq[k] += a[k] * a[k];
                }
                o[k] = (short)f2h(a[k]);
            }
            *(short8*)&dst[(size_t)n * drs + l * 8] = o;
        }
    }
    if (RS) {
        __shared__ float sh[256];
        int t = threadIdx.x;
        sh[t] = 0.f;
        __syncthreads();
#pragma unroll
        for (int k = 0; k < 8; ++k) {
            atomicAdd(&sh[l * 8 + k], ss[k]);
            atomicAdd(&sh[128 + l * 8 + k], qq[k]);
        }
        __syncthreads();
        if (t < 128)
            atomicAdd(&statS[t], sh[t]);
        else
            atomicAdd(&statQ[t - 128], sh[t]);
    }
}

// ---------------- half snapshot copy (tier B) ----------------
__global__ void k_copyh(const u16* __restrict__ src, u16* __restrict__ dst, int N) {
    int i = blockIdx.x * 256 + threadIdx.x;
    if (i >= N * 16) return;
    int n = i >> 4, c8 = (i & 15) * 8;
    *(short8*)&dst[(size_t)n * 128 + c8] = *(const short8*)&src[(size_t)n * 256 + c8];
}

__global__ void k_bnparam(const float* __restrict__ stats, const float* __restrict__ gamma,
                          const float* __restrict__ beta, float* __restrict__ st, int N) {
    int d = threadIdx.x;
    float inv = 1.f / (float)N;
    float mu = stats[d] * inv;
    float var = fmaxf(stats[256 + d] * inv - mu * mu, 0.f);
    float sc = gamma[d] * rsqrtf(var + 1e-5f);
    st[d] = sc;
    st[256 + d] = beta[d] - mu * sc;
}

__global__ void k_fold(const float* __restrict__ W, const float* __restrict__ st,
                       u16* __restrict__ Wp, float* __restrict__ cvec) {
    __shared__ float red[256];
    int o = blockIdx.x, k = threadIdx.x;
    float w = W[o * 256 + k];
    Wp[o * 256 + k] = f2h(w * st[k]);
    red[k] = w * st[256 + k];
    __syncthreads();
    for (int s = 128; s > 0; s >>= 1) {
        if (k < s) red[k] += red[k + s];
        __syncthreads();
    }
    if (k == 0) cvec[o] = red[0];
}

// ---------------- set2set GEMM: C[M,O](f16) = A[M,K](f16) @ W[O,K](f16)^T + cvec ----------------
__global__ __launch_bounds__(256, 2) void k_gemmf(const u16* __restrict__ A,
                                                  const u16* __restrict__ W,
                                                  const float* __restrict__ cvec,
                                                  u16* __restrict__ C, int M, int K, int O) {
    const int PAD = 8;
    __shared__ u16 As[128][64 + PAD];
    __shared__ u16 Ws[128][64 + PAD];
    int tM = blockIdx.x, tO = blockIdx.y;
    int tid = threadIdx.x;
    int lane = tid & 63, wid = tid >> 6;
    int wM = wid & 1, wO = wid >> 1;
    f32x4 acc[4][4] = {};
    size_t rowA0 = (size_t)tM * 128, rowW0 = (size_t)tO * 128;
    for (int k0 = 0; k0 < K; k0 += 64) {
#pragma unroll
        for (int i = 0; i < 4; ++i) {
            int chunk = tid + i * 256;
            int r = chunk >> 3, c16 = chunk & 7;
            *(short8*)&As[r][c16 * 8] = *(const short8*)&A[(rowA0 + r) * K + k0 + c16 * 8];
            *(short8*)&Ws[r][c16 * 8] = *(const short8*)&W[(rowW0 + r) * K + k0 + c16 * 8];
        }
        __syncthreads();
#pragma unroll
        for (int ks = 0; ks < 2; ++ks) {
            half8 af[4], wf[4];
#pragma unroll
            for (int m = 0; m < 4; ++m)
                af[m] = *(const half8*)&As[wM * 64 + m * 16 + (lane & 15)][ks * 32 + (lane >> 4) * 8];
#pragma unroll
            for (int o = 0; o < 4; ++o)
                wf[o] = *(const half8*)&Ws[wO * 64 + o * 16 + (lane & 15)][ks * 32 + (lane >> 4) * 8];
#pragma unroll
            for (int m = 0; m < 4; ++m)
#pragma unroll
                for (int o = 0; o < 4; ++o)
                    acc[m][o] = __builtin_amdgcn_mfma_f32_16x16x32_f16(af[m], wf[o], acc[m][o], 0, 0, 0);
        }
        __syncthreads();
    }
#pragma unroll
    for (int m = 0; m < 4; ++m) {
        int R0 = tM * 128 + wM * 64 + m * 16 + (lane >> 4) * 4;
#pragma unroll
        for (int o = 0; o < 4; ++o) {
            int Cc = tO * 128 + wO * 64 + o * 16 + (lane & 15);
            float cv = cvec[Cc];
#pragma unroll
            for (int r = 0; r < 4; ++r)
                C[(size_t)(R0 + r) * O + Cc] = f2h(acc[m][o][r] + cv);
        }
    }
}

// ---------------- set2set pieces ----------------
__global__ void k_wcat(const float* __restrict__ Wi, const float* __restrict__ Wh,
                       const float* __restrict__ bi, const float* __restrict__ bh,
                       u16* __restrict__ Wcat, float* __restrict__ bcat) {
    int o = blockIdx.x;
    int t = threadIdx.x;
    for (int c = t; c < 512; c += 256) Wcat[(size_t)o * 768 + c] = f2h(Wi[(size_t)o * 512 + c]);
    if (t < 256) Wcat[(size_t)o * 768 + 512 + t] = f2h(Wh[(size_t)o * 256 + t]);
    if (t == 0) bcat[o] = bi[o] + bh[o];
}

__global__ void k_lstm(const u16* __restrict__ gates, float* __restrict__ cs,
                       float* __restrict__ hsb, u16* __restrict__ qsh, int G) {
    int idx = blockIdx.x * 256 + threadIdx.x;
    if (idx >= G * 256) return;
    int g = idx >> 8, d = idx & 255;
    const u16* gt = &gates[(size_t)g * 1024];
    float gi = h2f(gt[d]), gf = h2f(gt[256 + d]), gg = h2f(gt[512 + d]), go = h2f(gt[768 + d]);
    float c = sigf(gf) * cs[idx] + sigf(gi) * tanhf(gg);
    float hh = sigf(go) * tanhf(c);
    cs[idx] = c;
    hsb[idx] = hh;
    u16 hb = f2h(hh);
    qsh[(size_t)g * 768 + d] = hb;
    qsh[(size_t)g * 768 + 512 + d] = hb;
}

// ---------------- attention: one wave per graph; h3 may be split across two buffers ----------------
__global__ __launch_bounds__(256) void k_attn2(const u16* __restrict__ lo, int lstr,
                                               const u16* __restrict__ hi, int hstr,
                                               const float* __restrict__ hs,
                                               const int* __restrict__ gstart,
                                               u16* __restrict__ qsh, int G) {
    int wid = threadIdx.x >> 6, lane = threadIdx.x & 63;
    int g = blockIdx.x * 4 + wid;
    if (g >= G) return;
    int start = gstart[g], end = gstart[g + 1];

    const u16* base = (lane < 32) ? lo : hi;
    size_t stride = (lane < 32) ? lstr : hstr;
    int coff = (lane < 32) ? lane * 4 : (lane - 32) * 4;

    f32x4 q = *(const f32x4*)&hs[(size_t)g * 256 + lane * 4];
    float m = -INFINITY, z = 0.f;
    float r0a = 0.f, r1a = 0.f, r2a = 0.f, r3a = 0.f;

    for (int c0 = start; c0 < end; c0 += 256) {
        int cn = min(256, end - c0);
        float e0 = 0.f, e1 = 0.f, e2 = 0.f, e3 = 0.f;
        float mc = m;

        auto pass1 = [&](int rr, float& ev) {
            int b = c0 + rr * 64;
            int nr = min(64, end - b);
            for (int ii = 0; ii < nr; ++ii) {
                u16x4 hv = *(const u16x4*)&base[(size_t)(b + ii) * stride + coff];
                float e = h2f(hv[0]) * q[0] + h2f(hv[1]) * q[1] + h2f(hv[2]) * q[2] + h2f(hv[3]) * q[3];
                e += __shfl_xor(e, 32, 64);
                e += __shfl_xor(e, 16, 64);
                e += __shfl_xor(e, 8, 64);
                e += __shfl_xor(e, 4, 64);
                e += __shfl_xor(e, 2, 64);
                e += __shfl_xor(e, 1, 64);
                if (lane == ii) ev = e;
                mc = fmaxf(mc, e);
            }
        };
        pass1(0, e0);
        pass1(1, e1);
        pass1(2, e2);
        pass1(3, e3);

        float rf = (m == -INFINITY) ? 0.f : expf(m - mc);
        float zc = 0.f;
        e0 = (lane < cn) ? expf(e0 - mc) : 0.f;
        zc += e0;
        e1 = (64 + lane < cn) ? expf(e1 - mc) : 0.f;
        zc += e1;
        e2 = (128 + lane < cn) ? expf(e2 - mc) : 0.f;
        zc += e2;
        e3 = (192 + lane < cn) ? expf(e3 - mc) : 0.f;
        zc += e3;
        zc += __shfl_xor(zc, 32, 64);
        zc += __shfl_xor(zc, 16, 64);
        zc += __shfl_xor(zc, 8, 64);
        zc += __shfl_xor(zc, 4, 64);
        zc += __shfl_xor(zc, 2, 64);
        zc += __shfl_xor(zc, 1, 64);
        z = z * rf + zc;
        r0a *= rf; r1a *= rf; r2a *= rf; r3a *= rf;

        auto pass2 = [&](int rr, float ev) {
            int b = c0 + rr * 64;
            int nr = min(64, end - b);
            for (int ii = 0; ii < nr; ++ii) {
                float w = __shfl(ev, ii, 64);
                u16x4 hv = *(const u16x4*)&base[(size_t)(b + ii) * stride + coff];
                r0a += w * h2f(hv[0]);
                r1a += w * h2f(hv[1]);
                r2a += w * h2f(hv[2]);
                r3a += w * h2f(hv[3]);
            }
        };
        pass2(0, e0);
        pass2(1, e1);
        pass2(2, e2);
        pass2(3, e3);
        m = mc;
    }
    float inv = (end > start) ? 1.f / fmaxf(z, 1e-30f) : 0.f;
    u16x4 o;
    o[0] = f2h(r0a * inv);
    o[1] = f2h(r1a * inv);
    o[2] = f2h(r2a * inv);
    o[3] = f2h(r3a * inv);
    int qcol = (lane < 32) ? lane * 4 : 128 + (lane - 32) * 4;
    *(u16x4*)&qsh[(size_t)g * 768 + 256 + qcol] = o;
}

// lin1/lin2 compose
__global__ void k_wfold(const float* __restrict__ l1W, const float* __restrict__ l1b,
                        const float* __restrict__ l2W, const float* __restrict__ l2b,
                        float* __restrict__ weff) {
    int c = blockIdx.x * 256 + threadIdx.x;
    if (c < 512) {
        float s = 0.f;
        for (int t = 0; t < 128; ++t) s += l2W[t] * l1W[(size_t)t * 512 + c];
        weff[c] = s;
    }
    if (c == 0) {
        float b = l2b[0];
        for (int t = 0; t < 128; ++t) b += l2W[t] * l1b[t];
        weff[512] = b;
    }
}

__global__ __launch_bounds__(256) void k_final2(const u16* __restrict__ qsh,
                                                const float* __restrict__ weff,
                                                float* __restrict__ out, int G) {
    __shared__ float wsm[513];
    int tid = threadIdx.x;
    for (int j = tid; j < 513; j += 256) wsm[j] = weff[j];
    __syncthreads();
    int g = blockIdx.x * 4 + (tid >> 6);
    int lane = tid & 63;
    if (g >= G) return;
    const u16* qp = &qsh[(size_t)g * 768];
    float s = 0.f;
#pragma unroll
    for (int j = 0; j < 8; ++j) s += h2f(qp[lane * 8 + j]) * wsm[lane * 8 + j];
    for (int off = 32; off; off >>= 1) s += __shfl_xor(s, off, 64);
    if (lane == 0) out[g] = sigf(s + wsm[512]);
}

// ---------------- host ----------------
extern "C" void kernel_launch(void* const* d_in, const int* in_sizes, int n_in,
                              void* d_out, int out_size, void* d_ws, size_t ws_size,
                              hipStream_t stream) {
    const int* x = (const int*)d_in[0];
    const int* ei = (const int*)d_in[1];
    const int* batch = (const int*)d_in[2];
    const float* atom_emb = (const float*)d_in[4];
    const float* W1 = (const float*)d_in[5];
    const float* b1 = (const float*)d_in[6];
    const float* W2 = (const float*)d_in[7];
    const float* b2 = (const float*)d_in[8];
    const float* W3 = (const float*)d_in[9];
    const float* b3 = (const float*)d_in[10];
    const float* gamma = (const float*)d_in[11];
    const float* beta = (const float*)d_in[12];
    const float* Wi = (const float*)d_in[13];
    const float* Wh = (const float*)d_in[14];
    const float* bi = (const float*)d_in[15];
    const float* bh = (const float*)d_in[16];
    const float* l1W = (const float*)d_in[17];
    const float* l1b = (const float*)d_in[18];
    const float* l2W = (const float*)d_in[19];
    const float* l2b = (const float*)d_in[20];

    const int N = in_sizes[0] / 9;
    const int E = in_sizes[1] / 2;
    const int G = out_size;
    const int* srcp = ei;
    const int* tgtp = ei + E;

    char* ws = (char*)d_ws;
    size_t off = 0;
    auto alloc = [&](size_t bytes) -> void* {
        void* p = ws + off;
        off += (bytes + 255) & ~(size_t)255;
        return p;
    };
    size_t xOff = off;
    u16* X = (u16*)alloc((size_t)N * 256 * 2);  // 128 MiB
    int* rp = (int*)alloc((size_t)N * 4);
    int2* est = (int2*)alloc((size_t)E * 8);
    float* dinv = (float*)alloc((size_t)N * 4);
    int* gstart = (int*)alloc((size_t)(G + 1) * 4);
    float* stats = (float*)alloc(512 * 4);
    float* stbuf = (float*)alloc(512 * 4);
    float* cvec = (float*)alloc(256 * 4);
    u16* Wp = (u16*)alloc(256 * 256 * 2);
    int* bsum = (int*)alloc(1024 * 4);
    float* weff = (float*)alloc(513 * 4);
    size_t offR = off;

    size_t halfB = ((size_t)N * 128 * 2 + 255) & ~(size_t)255;  // 64 MiB
    size_t s2sR = 0;
    {
        size_t t = 0;
        auto sz = [&](size_t b) { t += (b + 255) & ~(size_t)255; };
        sz((size_t)1024 * 768 * 2);  // Wcat
        sz(1024 * 4);                // bcat
        sz((size_t)G * 768 * 2);     // qsh
        sz((size_t)G * 1024 * 2);    // gates
        sz((size_t)G * 256 * 4);     // hsb
        sz((size_t)G * 256 * 4);     // csb
        s2sR = t;
    }
    size_t xBytes = ((size_t)N * 256 * 2 + 255) & ~(size_t)255;
    size_t needFull = offR + 2 * halfB;                   // Y,Y2; s2s aliases X (s2sR <= xBytes)
    size_t needA = offR + halfB + s2sR;                   // Y live through s2s
    size_t needB = offR + (halfB > s2sR ? halfB : s2sR);  // s2s aliases Y
    int tier = (ws_size >= needFull && s2sR <= xBytes) ? 2 : ws_size >= needA ? 1
               : ws_size >= needB ? 0 : -1;
    if (tier < 0) {
        k_diagf<<<(G + 255) / 256, 256, 0, stream>>>((float*)d_out, G, 12345.0f);
        return;
    }
    u16* Y = (u16*)(ws + offR);
    u16* Y2 = (u16*)(ws + offR + halfB);  // tierFull only
    size_t s2sBase = (tier == 2) ? xOff : (tier == 1) ? offR + halfB : offR;
    size_t o2 = s2sBase;
    auto alloc2 = [&](size_t bytes) -> void* {
        void* p = ws + o2;
        o2 += (bytes + 255) & ~(size_t)255;
        return p;
    };
    u16* Wcat = (u16*)alloc2((size_t)1024 * 768 * 2);
    float* bcat = (float*)alloc2(1024 * 4);
    u16* qsh = (u16*)alloc2((size_t)G * 768 * 2);
    u16* gates = (u16*)alloc2((size_t)G * 1024 * 2);
    float* hsb = (float*)alloc2((size_t)G * 256 * 4);
    float* csb = (float*)alloc2((size_t)G * 256 * 4);

    // embed + segment starts + CSR
    k_embed<<<N / 8, 256, 0, stream>>>(x, atom_emb, X, N);
    k_gstart<<<(N + 255) / 256, 256, 0, stream>>>(batch, gstart, N, G);
    k_zero_int<<<(N + 255) / 256, 256, 0, stream>>>(rp, N);
    k_count<<<(E + 255) / 256, 256, 0, stream>>>(tgtp, rp, E);
    k_dinv<<<(N + 255) / 256, 256, 0, stream>>>(rp, dinv, N);
    int nb1 = (N + 1023) / 1024;
    k_scan1<<<nb1, 256, 0, stream>>>(rp, bsum, N);
    k_scan2<<<1, 256, 0, stream>>>(bsum, nb1);
    k_scan3<<<(N + 255) / 256, 256, 0, stream>>>(rp, bsum, N);
    k_fill<<<(E + 255) / 256, 256, 0, stream>>>(srcp, tgtp, rp, dinv, est, E);

    int gipb = N / 64;
    int cpb = (N * 16 + 255) / 256;
    int aggb = (N / 4 + 15) / 16;
    int aggfb = (N / 4 + 7) / 8;

    const u16 *h3lo, *h3hi;
    int h3ls, h3hs;
    if (tier == 2) {
        // Full: GEMM -> X full rows; aggf X -> (Y lo, Y2 hi); next GEMM reads (Y, Y2).
        for (int conv = 0; conv < 3; ++conv) {
            const float* Wsrc = conv == 0 ? W1 : (conv == 1 ? W2 : W3);
            const float* bsrc = conv == 0 ? b1 : (conv == 1 ? b2 : b3);
            bool rs = conv < 2;
            if (conv == 0)
                k_cvtW<<<256, 256, 0, stream>>>(Wsrc, Wp, 65536);
            else
                k_fold<<<256, 256, 0, stream>>>(Wsrc, stbuf, Wp, cvec);
            if (rs) k_zero_f32<<<2, 256, 0, stream>>>(stats, 512);
            if (conv == 0)
                k_gemm<<<gipb, 256, 0, stream>>>(X, 256, X + 128, 256, Wp, nullptr, X, N);
            else
                k_gemm<<<gipb, 256, 0, stream>>>(Y, 128, Y2, 128, Wp, cvec, X, N);
            if (rs)
                k_aggf<true><<<aggfb, 256, 0, stream>>>(X, Y, Y2, rp, est, dinv, bsrc, stats, N);
            else
                k_aggf<false><<<aggfb, 256, 0, stream>>>(X, Y, Y2, rp, est, dinv, bsrc, nullptr, N);
            if (rs) k_bnparam<<<1, 256, 0, stream>>>(stats, gamma, beta, stbuf, N);
        }
        h3lo = Y; h3ls = 128; h3hi = Y2; h3hs = 128;  // X dead -> s2s aliases X
    } else {
        // Tier A/B rotation/copy paths (proven)
        k_cvtW<<<256, 256, 0, stream>>>(W1, Wp, 65536);
        k_zero_f32<<<2, 256, 0, stream>>>(stats, 512);
        k_gemm<<<gipb, 256, 0, stream>>>(X, 256, X + 128, 256, Wp, nullptr, X, N);
        k_aggh<true><<<aggb, 256, 0, stream>>>(X, 256, Y, 128, rp, est, dinv, b1, stats, stats + 256, N);
        k_aggh<true><<<aggb, 256, 0, stream>>>(X + 128, 256, X, 256, rp, est, dinv, b1 + 128, stats + 128, stats + 384, N);
        k_bnparam<<<1, 256, 0, stream>>>(stats, gamma, beta, stbuf, N);

        k_fold<<<256, 256, 0, stream>>>(W2, stbuf, Wp, cvec);
        k_zero_f32<<<2, 256, 0, stream>>>(stats, 512);
        k_gemm<<<gipb, 256, 0, stream>>>(Y, 128, X, 256, Wp, cvec, X, N);
        k_aggh<true><<<aggb, 256, 0, stream>>>(X, 256, Y, 128, rp, est, dinv, b2, stats, stats + 256, N);
        k_aggh<true><<<aggb, 256, 0, stream>>>(X + 128, 256, X, 256, rp, est, dinv, b2 + 128, stats + 128, stats + 384, N);
        k_bnparam<<<1, 256, 0, stream>>>(stats, gamma, beta, stbuf, N);

        k_fold<<<256, 256, 0, stream>>>(W3, stbuf, Wp, cvec);
        k_gemm<<<gipb, 256, 0, stream>>>(Y, 128, X, 256, Wp, cvec, X, N);
        if (tier == 1) {
            k_aggh<false><<<aggb, 256, 0, stream>>>(X, 256, Y, 128, rp, est, dinv, b3, nullptr, nullptr, N);
            k_aggh<false><<<aggb, 256, 0, stream>>>(X + 128, 256, X, 256, rp, est, dinv, b3 + 128, nullptr, nullptr, N);
            h3lo = Y; h3ls = 128; h3hi = X; h3hs = 256;
        } else {
            k_copyh<<<cpb, 256, 0, stream>>>(X, Y, N);
            k_aggh<false><<<aggb, 256, 0, stream>>>(Y, 128, X, 256, rp, est, dinv, b3, nullptr, nullptr, N);
            k_copyh<<<cpb, 256, 0, stream>>>(X + 128, Y, N);
            k_aggh<false><<<aggb, 256, 0, stream>>>(Y, 128, X + 128, 256, rp, est, dinv, b3 + 128, nullptr, nullptr, N);
            h3lo = X; h3ls = 256; h3hi = X + 128; h3hs = 256;
        }
    }

    // set2set
    k_wcat<<<1024, 256, 0, stream>>>(Wi, Wh, bi, bh, Wcat, bcat);
    k_zero_u16<<<(G * 768 + 255) / 256, 256, 0, stream>>>(qsh, G * 768);
    k_zero_f32<<<(G * 256 + 255) / 256, 256, 0, stream>>>(csb, G * 256);
    dim3 ggates(G / 128, 8);
    for (int s = 0; s < 4; ++s) {
        k_gemmf<<<ggates, 256, 0, stream>>>(qsh, Wcat, bcat, gates, G, 768, 1024);
        k_lstm<<<(G * 256 + 255) / 256, 256, 0, stream>>>(gates, csb, hsb, qsh, G);
        k_attn2<<<(G + 3) / 4, 256, 0, stream>>>(h3lo, h3ls, h3hi, h3hs, hsb, gstart, qsh, G);
    }
    k_wfold<<<2, 256, 0, stream>>>(l1W, l1b, l2W, l2b, weff);
    k_final2<<<(G + 3) / 4, 256, 0, stream>>>(qsh, weff, (float*)d_out, G);
}

// Round 15
// 1424.639 us; speedup vs baseline: 1.0434x; 1.0333x over previous
//
#include <hip/hip_runtime.h>
#include <hip/hip_bf16.h>
#include <math.h>

using u16 = unsigned short;
typedef __attribute__((ext_vector_type(8))) short short8;
typedef __attribute__((ext_vector_type(8))) _Float16 half8;
typedef __attribute__((ext_vector_type(4))) float f32x4;
typedef __attribute__((ext_vector_type(4))) u16 u16x4;

__device__ __constant__ int c_OFF[9] = {0, 119, 123, 135, 147, 157, 163, 169, 171};

__device__ __forceinline__ float h2f(u16 u) {
    _Float16 h;
    __builtin_memcpy(&h, &u, 2);
    return (float)h;
}
__device__ __forceinline__ u16 f2h(float f) {
    _Float16 h = (_Float16)f;
    u16 u;
    __builtin_memcpy(&u, &h, 2);
    return u;
}
__device__ __forceinline__ float sigf(float x) { return 1.f / (1.f + expf(-x)); }

// ---------------- diagnostics ----------------
__global__ void k_diagf(float* out, int G, float val) {
    int i = blockIdx.x * 256 + threadIdx.x;
    if (i < G) out[i] = val;
}

// ---------------- zero helpers ----------------
__global__ void k_zero_f32(float* p, int n) {
    int i = blockIdx.x * 256 + threadIdx.x;
    if (i < n) p[i] = 0.f;
}
__global__ void k_zero_int(int* p, int n) {
    int i = blockIdx.x * 256 + threadIdx.x;
    if (i < n) p[i] = 0;
}

// ---------------- fp32 -> fp16 convert ----------------
__global__ void k_cvtW(const float* __restrict__ src, u16* __restrict__ dst, int n) {
    int i = blockIdx.x * 256 + threadIdx.x;
    if (i < n) dst[i] = f2h(src[i]);
}

// ---------------- atom encoder: 8 nodes/block, 8 cols/thread, vectorized ----------------
__global__ __launch_bounds__(256) void k_embed(const int* __restrict__ x,
                                               const float* __restrict__ emb,
                                               u16* __restrict__ out, int N) {
    __shared__ int rows[72];
    int nb = blockIdx.x * 8;
    int tid = threadIdx.x;
    if (tid < 72) rows[tid] = x[(size_t)nb * 9 + tid] + c_OFF[tid % 9];
    __syncthreads();
    int ln = tid >> 5;
    int c8 = (tid & 31) * 8;
    float s0 = 0.f, s1 = 0.f, s2 = 0.f, s3 = 0.f, s4 = 0.f, s5 = 0.f, s6 = 0.f, s7 = 0.f;
#pragma unroll
    for (int c = 0; c < 9; ++c) {
        int r = rows[ln * 9 + c];
        f32x4 a = *(const f32x4*)&emb[r * 256 + c8];
        f32x4 b = *(const f32x4*)&emb[r * 256 + c8 + 4];
        s0 += a[0]; s1 += a[1]; s2 += a[2]; s3 += a[3];
        s4 += b[0]; s5 += b[1]; s6 += b[2]; s7 += b[3];
    }
    short8 o;
    o[0] = (short)f2h(s0); o[1] = (short)f2h(s1); o[2] = (short)f2h(s2); o[3] = (short)f2h(s3);
    o[4] = (short)f2h(s4); o[5] = (short)f2h(s5); o[6] = (short)f2h(s6); o[7] = (short)f2h(s7);
    *(short8*)&out[(size_t)(nb + ln) * 256 + c8] = o;
}

// ---------------- graph segment starts from sorted batch ----------------
__global__ void k_gstart(const int* __restrict__ batch, int* __restrict__ gstart, int N, int G) {
    int i = blockIdx.x * 256 + threadIdx.x;
    if (i >= N) return;
    int b = batch[i];
    if (i == 0) {
        for (int g = 0; g <= b; ++g) gstart[g] = 0;
    } else {
        int p = batch[i - 1];
        for (int g = p + 1; g <= b; ++g) gstart[g] = i;
    }
    if (i == N - 1) {
        for (int g = b + 1; g <= G; ++g) gstart[g] = N;
    }
}

// ---------------- CSR build (in-place in rp) ----------------
__global__ void k_count(const int* __restrict__ tgt, int* rp, int E) {
    int e = blockIdx.x * 256 + threadIdx.x;
    if (e < E) atomicAdd(&rp[tgt[e]], 1);
}

__global__ void k_dinv(const int* __restrict__ cnt, float* __restrict__ dinv, int N) {
    int i = blockIdx.x * 256 + threadIdx.x;
    if (i < N) dinv[i] = rsqrtf((float)cnt[i] + 1.f);
}

__global__ void k_scan1(int* __restrict__ rp, int* __restrict__ bsum, int N) {
    int t = threadIdx.x;
    int base = blockIdx.x * 1024 + t * 4;
    int v0 = 0, v1 = 0, v2 = 0, v3 = 0;
    if (base + 3 < N) {
        v0 = rp[base]; v1 = rp[base + 1]; v2 = rp[base + 2]; v3 = rp[base + 3];
    } else {
        if (base < N) v0 = rp[base];
        if (base + 1 < N) v1 = rp[base + 1];
        if (base + 2 < N) v2 = rp[base + 2];
    }
    int s = v0 + v1 + v2 + v3;
    int lane = t & 63, w = t >> 6;
    int x = s;
    for (int o = 1; o < 64; o <<= 1) {
        int y = __shfl_up(x, o, 64);
        if (lane >= o) x += y;
    }
    __shared__ int wsum[4];
    if (lane == 63) wsum[w] = x;
    __syncthreads();
    int woff = 0;
    for (int i = 0; i < w; ++i) woff += wsum[i];
    int excl = woff + x - s;
    if (base < N) rp[base] = excl;
    if (base + 1 < N) rp[base + 1] = excl + v0;
    if (base + 2 < N) rp[base + 2] = excl + v0 + v1;
    if (base + 3 < N) rp[base + 3] = excl + v0 + v1 + v2;
    if (t == 255) bsum[blockIdx.x] = wsum[0] + wsum[1] + wsum[2] + wsum[3];
}

__global__ void k_scan2(int* bsum, int nb) {
    int t = threadIdx.x;
    int s = (t < nb) ? bsum[t] : 0;
    int lane = t & 63, w = t >> 6;
    int x = s;
    for (int o = 1; o < 64; o <<= 1) {
        int y = __shfl_up(x, o, 64);
        if (lane >= o) x += y;
    }
    __shared__ int wsum[4];
    if (lane == 63) wsum[w] = x;
    __syncthreads();
    int woff = 0;
    for (int i = 0; i < w; ++i) woff += wsum[i];
    if (t < nb) bsum[t] = woff + x - s;
}

__global__ void k_scan3(int* __restrict__ rp, const int* __restrict__ bsum, int N) {
    int i = blockIdx.x * 256 + threadIdx.x;
    if (i < N) rp[i] += bsum[i >> 10];
}

// fill with packed (src, norm); afterwards rp[n] = end(n), start(n) = rp[n-1]
__global__ void k_fill(const int* __restrict__ src, const int* __restrict__ tgt,
                       int* __restrict__ rp, const float* __restrict__ dinv,
                       int2* __restrict__ est, int E) {
    int e = blockIdx.x * 256 + threadIdx.x;
    if (e < E) {
        int t = tgt[e];
        int s = src[e];
        int p = atomicAdd(&rp[t], 1);
        est[p] = make_int2(s, __float_as_int(dinv[s] * dinv[t]));
    }
}

// ---------------- GEMM: out[64 rows of X] <- A(from two half-buffers) @ Wp^T (+cvec) ----------------
__global__ __launch_bounds__(256, 3) void k_gemm(const u16* __restrict__ p0, int rs0,
                                                 const u16* __restrict__ p1, int rs1,
                                                 const u16* __restrict__ W,
                                                 const float* __restrict__ cvec,
                                                 u16* __restrict__ out, int N) {
    __shared__ u16 As[64][260];
    __shared__ u16 Ws[256][36];
    int r0 = blockIdx.x * 64;
    int tid = threadIdx.x, lane = tid & 63, w = tid >> 6;
#pragma unroll
    for (int i = 0; i < 8; ++i) {
        int chunk = i * 256 + tid;
        int r = chunk >> 5, c8 = chunk & 31;
        const u16* sp = (c8 < 16) ? &p0[(size_t)(r0 + r) * rs0 + c8 * 8]
                                  : &p1[(size_t)(r0 + r) * rs1 + (c8 - 16) * 8];
        *(short8*)&As[r][c8 * 8] = *(const short8*)sp;
    }
    f32x4 acc[16];
#pragma unroll
    for (int o = 0; o < 16; ++o) acc[o] = f32x4{0.f, 0.f, 0.f, 0.f};
    for (int k0 = 0; k0 < 256; k0 += 32) {
        __syncthreads();
#pragma unroll
        for (int i = 0; i < 4; ++i) {
            int chunk = i * 256 + tid;
            int r = chunk >> 2, c8 = chunk & 3;
            *(short8*)&Ws[r][c8 * 8] = *(const short8*)&W[(size_t)r * 256 + k0 + c8 * 8];
        }
        __syncthreads();
        half8 af = *(const half8*)&As[w * 16 + (lane & 15)][k0 + (lane >> 4) * 8];
#pragma unroll
        for (int o = 0; o < 16; ++o) {
            half8 wf = *(const half8*)&Ws[o * 16 + (lane & 15)][(lane >> 4) * 8];
            acc[o] = __builtin_amdgcn_mfma_f32_16x16x32_f16(af, wf, acc[o], 0, 0, 0);
        }
    }
    __syncthreads();
#pragma unroll
    for (int o = 0; o < 16; ++o) {
        int col = o * 16 + (lane & 15);
        float cv = cvec ? cvec[col] : 0.f;
#pragma unroll
        for (int r = 0; r < 4; ++r) {
            int row = w * 16 + (lane >> 4) * 4 + r;
            As[row][col] = f2h(acc[o][r] + cv);
        }
    }
    __syncthreads();
#pragma unroll
    for (int i = 0; i < 8; ++i) {
        int chunk = i * 256 + tid;
        int r = chunk >> 5, c8 = chunk & 31;
        *(short8*)&out[(size_t)(r0 + r) * 256 + c8 * 8] = *(const short8*)&As[r][c8 * 8];
    }
}

// ---------------- half aggregation: est BURST + register-address gathers ----------------
// 16-lane sub-wave per 4-node chunk. One coalesced est burst (16 edges), then a fully
// unrolled 16-step loop of INDEPENDENT predicated gathers (addresses from __shfl regs).
template <bool RS>
__global__ __launch_bounds__(256) void k_aggh(const u16* __restrict__ src, int srs,
                                              u16* __restrict__ dst, int drs,
                                              const int* __restrict__ rp,
                                              const int2* __restrict__ est,
                                              const float* __restrict__ dinv,
                                              const float* __restrict__ biasH,
                                              float* __restrict__ statS,
                                              float* __restrict__ statQ, int N) {
    int l = threadIdx.x & 15;
    int sub = blockIdx.x * 16 + (threadIdx.x >> 4);
    int n0 = sub * 4;
    float bv[8];
#pragma unroll
    for (int k = 0; k < 8; ++k) bv[k] = biasH[l * 8 + k];
    float ss[8] = {}, qq[8] = {};
    if (n0 < N) {
        int r0 = n0 ? rp[n0 - 1] : 0;
        int r1 = rp[n0], r2 = rp[n0 + 1], r3 = rp[n0 + 2], r4 = rp[n0 + 3];
        float d0 = dinv[n0], d1 = dinv[n0 + 1], d2 = dinv[n0 + 2], d3 = dinv[n0 + 3];
        short8 h0 = *(const short8*)&src[(size_t)n0 * srs + l * 8];
        short8 h1 = *(const short8*)&src[(size_t)(n0 + 1) * srs + l * 8];
        short8 h2 = *(const short8*)&src[(size_t)(n0 + 2) * srs + l * 8];
        short8 h3 = *(const short8*)&src[(size_t)(n0 + 3) * srs + l * 8];
        float a0[8], a1[8], a2[8], a3[8];
#pragma unroll
        for (int k = 0; k < 8; ++k) {
            a0[k] = h2f((u16)h0[k]) * d0 * d0 + bv[k];
            a1[k] = h2f((u16)h1[k]) * d1 * d1 + bv[k];
            a2[k] = h2f((u16)h2[k]) * d2 * d2 + bv[k];
            a3[k] = h2f((u16)h3[k]) * d3 * d3 + bv[k];
        }
        for (int base = r0; base < r4; base += 16) {
            int gl = base + l;
            int2 eL = est[gl < r4 ? gl : r4 - 1];  // coalesced burst, clamped
#pragma unroll
            for (int j = 0; j < 16; ++j) {
                int gj = base + j;
                if (gj < r4) {  // uniform per sub-wave -> exec-masked, no wasted loads
                    int sx = __shfl(eL.x, j, 16);
                    float nr = __int_as_float(__shfl(eL.y, j, 16));
                    float m0 = (gj < r1) ? nr : 0.f;
                    float m1 = (gj >= r1 && gj < r2) ? nr : 0.f;
                    float m2 = (gj >= r2 && gj < r3) ? nr : 0.f;
                    float m3 = (gj >= r3) ? nr : 0.f;
                    short8 v = *(const short8*)&src[(size_t)sx * srs + l * 8];
#pragma unroll
                    for (int k = 0; k < 8; ++k) {
                        float f = h2f((u16)v[k]);
                        a0[k] += f * m0;
                        a1[k] += f * m1;
                        a2[k] += f * m2;
                        a3[k] += f * m3;
                    }
                }
            }
        }
        short8 o0, o1, o2, o3;
#pragma unroll
        for (int k = 0; k < 8; ++k) {
            if (RS) {
                a0[k] = fmaxf(a0[k], 0.f); a1[k] = fmaxf(a1[k], 0.f);
                a2[k] = fmaxf(a2[k], 0.f); a3[k] = fmaxf(a3[k], 0.f);
                ss[k] += a0[k] + a1[k] + a2[k] + a3[k];
                qq[k] += a0[k] * a0[k] + a1[k] * a1[k] + a2[k] * a2[k] + a3[k] * a3[k];
            }
            o0[k] = (short)f2h(a0[k]); o1[k] = (short)f2h(a1[k]);
            o2[k] = (short)f2h(a2[k]); o3[k] = (short)f2h(a3[k]);
        }
        *(short8*)&dst[(size_t)n0 * drs + l * 8] = o0;
        *(short8*)&dst[(size_t)(n0 + 1) * drs + l * 8] = o1;
        *(short8*)&dst[(size_t)(n0 + 2) * drs + l * 8] = o2;
        *(short8*)&dst[(size_t)(n0 + 3) * drs + l * 8] = o3;
    }
    if (RS) {
        __shared__ float sh[256];
        int t = threadIdx.x;
        sh[t] = 0.f;
        __syncthreads();
#pragma unroll
        for (int k = 0; k < 8; ++k) {
            atomicAdd(&sh[l * 8 + k], ss[k]);
            atomicAdd(&sh[128 + l * 8 + k], qq[k]);
        }
        __syncthreads();
        if (t < 128)
            atomicAdd(&statS[t], sh[t]);
        else
            atomicAdd(&statQ[t - 128], sh[t]);
    }
}

// ---------------- half snapshot copy (tier B) ----------------
__global__ void k_copyh(const u16* __restrict__ src, u16* __restrict__ dst, int N) {
    int i = blockIdx.x * 256 + threadIdx.x;
    if (i >= N * 16) return;
    int n = i >> 4, c8 = (i & 15) * 8;
    *(short8*)&dst[(size_t)n * 128 + c8] = *(const short8*)&src[(size_t)n * 256 + c8];
}

__global__ void k_bnparam(const float* __restrict__ stats, const float* __restrict__ gamma,
                          const float* __restrict__ beta, float* __restrict__ st, int N) {
    int d = threadIdx.x;
    float inv = 1.f / (float)N;
    float mu = stats[d] * inv;
    float var = fmaxf(stats[256 + d] * inv - mu * mu, 0.f);
    float sc = gamma[d] * rsqrtf(var + 1e-5f);
    st[d] = sc;
    st[256 + d] = beta[d] - mu * sc;
}

__global__ void k_fold(const float* __restrict__ W, const float* __restrict__ st,
                       u16* __restrict__ Wp, float* __restrict__ cvec) {
    __shared__ float red[256];
    int o = blockIdx.x, k = threadIdx.x;
    float w = W[o * 256 + k];
    Wp[o * 256 + k] = f2h(w * st[k]);
    red[k] = w * st[256 + k];
    __syncthreads();
    for (int s = 128; s > 0; s >>= 1) {
        if (k < s) red[k] += red[k + s];
        __syncthreads();
    }
    if (k == 0) cvec[o] = red[0];
}

// ---------------- set2set GEMM: C[M,O](f16) = A[M,K](f16) @ W[O,K](f16)^T + cvec ----------------
__global__ __launch_bounds__(256, 2) void k_gemmf(const u16* __restrict__ A,
                                                  const u16* __restrict__ W,
                                                  const float* __restrict__ cvec,
                                                  u16* __restrict__ C, int M, int K, int O) {
    const int PAD = 8;
    __shared__ u16 As[128][64 + PAD];
    __shared__ u16 Ws[128][64 + PAD];
    int tM = blockIdx.x, tO = blockIdx.y;
    int tid = threadIdx.x;
    int lane = tid & 63, wid = tid >> 6;
    int wM = wid & 1, wO = wid >> 1;
    f32x4 acc[4][4] = {};
    size_t rowA0 = (size_t)tM * 128, rowW0 = (size_t)tO * 128;
    for (int k0 = 0; k0 < K; k0 += 64) {
#pragma unroll
        for (int i = 0; i < 4; ++i) {
            int chunk = tid + i * 256;
            int r = chunk >> 3, c16 = chunk & 7;
            *(short8*)&As[r][c16 * 8] = *(const short8*)&A[(rowA0 + r) * K + k0 + c16 * 8];
            *(short8*)&Ws[r][c16 * 8] = *(const short8*)&W[(rowW0 + r) * K + k0 + c16 * 8];
        }
        __syncthreads();
#pragma unroll
        for (int ks = 0; ks < 2; ++ks) {
            half8 af[4], wf[4];
#pragma unroll
            for (int m = 0; m < 4; ++m)
                af[m] = *(const half8*)&As[wM * 64 + m * 16 + (lane & 15)][ks * 32 + (lane >> 4) * 8];
#pragma unroll
            for (int o = 0; o < 4; ++o)
                wf[o] = *(const half8*)&Ws[wO * 64 + o * 16 + (lane & 15)][ks * 32 + (lane >> 4) * 8];
#pragma unroll
            for (int m = 0; m < 4; ++m)
#pragma unroll
                for (int o = 0; o < 4; ++o)
                    acc[m][o] = __builtin_amdgcn_mfma_f32_16x16x32_f16(af[m], wf[o], acc[m][o], 0, 0, 0);
        }
        __syncthreads();
    }
#pragma unroll
    for (int m = 0; m < 4; ++m) {
        int R0 = tM * 128 + wM * 64 + m * 16 + (lane >> 4) * 4;
#pragma unroll
        for (int o = 0; o < 4; ++o) {
            int Cc = tO * 128 + wO * 64 + o * 16 + (lane & 15);
            float cv = cvec[Cc];
#pragma unroll
            for (int r = 0; r < 4; ++r)
                C[(size_t)(R0 + r) * O + Cc] = f2h(acc[m][o][r] + cv);
        }
    }
}

// ---------------- set2set pieces ----------------
__global__ void k_wcat(const float* __restrict__ Wi, const float* __restrict__ Wh,
                       const float* __restrict__ bi, const float* __restrict__ bh,
                       u16* __restrict__ Wcat, float* __restrict__ bcat) {
    int o = blockIdx.x;
    int t = threadIdx.x;
    for (int c = t; c < 512; c += 256) Wcat[(size_t)o * 768 + c] = f2h(Wi[(size_t)o * 512 + c]);
    if (t < 256) Wcat[(size_t)o * 768 + 512 + t] = f2h(Wh[(size_t)o * 256 + t]);
    if (t == 0) bcat[o] = bi[o] + bh[o];
}

// step-0 gates: q_star = hs = 0, so gates row = bcat (broadcast)
__global__ void k_gates0(const float* __restrict__ bcat, u16* __restrict__ gates, int G) {
    __shared__ u16 bh[1024];
    int t = threadIdx.x;
#pragma unroll
    for (int j = 0; j < 4; ++j) bh[t + j * 256] = f2h(bcat[t + j * 256]);
    __syncthreads();
    // each block writes 8 graph rows
    int g0 = blockIdx.x * 8;
    for (int r = 0; r < 8; ++r) {
        int g = g0 + r;
        if (g >= G) return;
#pragma unroll
        for (int j = 0; j < 4; ++j)
            gates[(size_t)g * 1024 + t + j * 256] = bh[t + j * 256];
    }
}

__global__ void k_lstm(const u16* __restrict__ gates, float* __restrict__ cs,
                       float* __restrict__ hsb, u16* __restrict__ qsh, int G) {
    int idx = blockIdx.x * 256 + threadIdx.x;
    if (idx >= G * 256) return;
    int g = idx >> 8, d = idx & 255;
    const u16* gt = &gates[(size_t)g * 1024];
    float gi = h2f(gt[d]), gf = h2f(gt[256 + d]), gg = h2f(gt[512 + d]), go = h2f(gt[768 + d]);
    float c = sigf(gf) * cs[idx] + sigf(gi) * tanhf(gg);
    float hh = sigf(go) * tanhf(c);
    cs[idx] = c;
    hsb[idx] = hh;
    u16 hb = f2h(hh);
    qsh[(size_t)g * 768 + d] = hb;
    qsh[(size_t)g * 768 + 512 + d] = hb;
}

// ---------------- attention: one wave per graph; h3 may be split across two buffers ----------------
__global__ __launch_bounds__(256) void k_attn2(const u16* __restrict__ lo, int lstr,
                                               const u16* __restrict__ hi, int hstr,
                                               const float* __restrict__ hs,
                                               const int* __restrict__ gstart,
                                               u16* __restrict__ qsh, int G) {
    int wid = threadIdx.x >> 6, lane = threadIdx.x & 63;
    int g = blockIdx.x * 4 + wid;
    if (g >= G) return;
    int start = gstart[g], end = gstart[g + 1];

    const u16* base = (lane < 32) ? lo : hi;
    size_t stride = (lane < 32) ? lstr : hstr;
    int coff = (lane < 32) ? lane * 4 : (lane - 32) * 4;

    f32x4 q = *(const f32x4*)&hs[(size_t)g * 256 + lane * 4];
    float m = -INFINITY, z = 0.f;
    float r0a = 0.f, r1a = 0.f, r2a = 0.f, r3a = 0.f;

    for (int c0 = start; c0 < end; c0 += 256) {
        int cn = min(256, end - c0);
        float e0 = 0.f, e1 = 0.f, e2 = 0.f, e3 = 0.f;
        float mc = m;

        auto pass1 = [&](int rr, float& ev) {
            int b = c0 + rr * 64;
            int nr = min(64, end - b);
            for (int ii = 0; ii < nr; ++ii) {
                u16x4 hv = *(const u16x4*)&base[(size_t)(b + ii) * stride + coff];
                float e = h2f(hv[0]) * q[0] + h2f(hv[1]) * q[1] + h2f(hv[2]) * q[2] + h2f(hv[3]) * q[3];
                e += __shfl_xor(e, 32, 64);
                e += __shfl_xor(e, 16, 64);
                e += __shfl_xor(e, 8, 64);
                e += __shfl_xor(e, 4, 64);
                e += __shfl_xor(e, 2, 64);
                e += __shfl_xor(e, 1, 64);
                if (lane == ii) ev = e;
                mc = fmaxf(mc, e);
            }
        };
        pass1(0, e0);
        pass1(1, e1);
        pass1(2, e2);
        pass1(3, e3);

        float rf = (m == -INFINITY) ? 0.f : expf(m - mc);
        float zc = 0.f;
        e0 = (lane < cn) ? expf(e0 - mc) : 0.f;
        zc += e0;
        e1 = (64 + lane < cn) ? expf(e1 - mc) : 0.f;
        zc += e1;
        e2 = (128 + lane < cn) ? expf(e2 - mc) : 0.f;
        zc += e2;
        e3 = (192 + lane < cn) ? expf(e3 - mc) : 0.f;
        zc += e3;
        zc += __shfl_xor(zc, 32, 64);
        zc += __shfl_xor(zc, 16, 64);
        zc += __shfl_xor(zc, 8, 64);
        zc += __shfl_xor(zc, 4, 64);
        zc += __shfl_xor(zc, 2, 64);
        zc += __shfl_xor(zc, 1, 64);
        z = z * rf + zc;
        r0a *= rf; r1a *= rf; r2a *= rf; r3a *= rf;

        auto pass2 = [&](int rr, float ev) {
            int b = c0 + rr * 64;
            int nr = min(64, end - b);
            for (int ii = 0; ii < nr; ++ii) {
                float w = __shfl(ev, ii, 64);
                u16x4 hv = *(const u16x4*)&base[(size_t)(b + ii) * stride + coff];
                r0a += w * h2f(hv[0]);
                r1a += w * h2f(hv[1]);
                r2a += w * h2f(hv[2]);
                r3a += w * h2f(hv[3]);
            }
        };
        pass2(0, e0);
        pass2(1, e1);
        pass2(2, e2);
        pass2(3, e3);
        m = mc;
    }
    float inv = (end > start) ? 1.f / fmaxf(z, 1e-30f) : 0.f;
    u16x4 o;
    o[0] = f2h(r0a * inv);
    o[1] = f2h(r1a * inv);
    o[2] = f2h(r2a * inv);
    o[3] = f2h(r3a * inv);
    int qcol = (lane < 32) ? lane * 4 : 128 + (lane - 32) * 4;
    *(u16x4*)&qsh[(size_t)g * 768 + 256 + qcol] = o;
}

// lin1/lin2 compose
__global__ void k_wfold(const float* __restrict__ l1W, const float* __restrict__ l1b,
                        const float* __restrict__ l2W, const float* __restrict__ l2b,
                        float* __restrict__ weff) {
    int c = blockIdx.x * 256 + threadIdx.x;
    if (c < 512) {
        float s = 0.f;
        for (int t = 0; t < 128; ++t) s += l2W[t] * l1W[(size_t)t * 512 + c];
        weff[c] = s;
    }
    if (c == 0) {
        float b = l2b[0];
        for (int t = 0; t < 128; ++t) b += l2W[t] * l1b[t];
        weff[512] = b;
    }
}

__global__ __launch_bounds__(256) void k_final2(const u16* __restrict__ qsh,
                                                const float* __restrict__ weff,
                                                float* __restrict__ out, int G) {
    __shared__ float wsm[513];
    int tid = threadIdx.x;
    for (int j = tid; j < 513; j += 256) wsm[j] = weff[j];
    __syncthreads();
    int g = blockIdx.x * 4 + (tid >> 6);
    int lane = tid & 63;
    if (g >= G) return;
    const u16* qp = &qsh[(size_t)g * 768];
    float s = 0.f;
#pragma unroll
    for (int j = 0; j < 8; ++j) s += h2f(qp[lane * 8 + j]) * wsm[lane * 8 + j];
    for (int off = 32; off; off >>= 1) s += __shfl_xor(s, off, 64);
    if (lane == 0) out[g] = sigf(s + wsm[512]);
}

// ---------------- host ----------------
extern "C" void kernel_launch(void* const* d_in, const int* in_sizes, int n_in,
                              void* d_out, int out_size, void* d_ws, size_t ws_size,
                              hipStream_t stream) {
    const int* x = (const int*)d_in[0];
    const int* ei = (const int*)d_in[1];
    const int* batch = (const int*)d_in[2];
    const float* atom_emb = (const float*)d_in[4];
    const float* W1 = (const float*)d_in[5];
    const float* b1 = (const float*)d_in[6];
    const float* W2 = (const float*)d_in[7];
    const float* b2 = (const float*)d_in[8];
    const float* W3 = (const float*)d_in[9];
    const float* b3 = (const float*)d_in[10];
    const float* gamma = (const float*)d_in[11];
    const float* beta = (const float*)d_in[12];
    const float* Wi = (const float*)d_in[13];
    const float* Wh = (const float*)d_in[14];
    const float* bi = (const float*)d_in[15];
    const float* bh = (const float*)d_in[16];
    const float* l1W = (const float*)d_in[17];
    const float* l1b = (const float*)d_in[18];
    const float* l2W = (const float*)d_in[19];
    const float* l2b = (const float*)d_in[20];

    const int N = in_sizes[0] / 9;
    const int E = in_sizes[1] / 2;
    const int G = out_size;
    const int* srcp = ei;
    const int* tgtp = ei + E;

    char* ws = (char*)d_ws;
    size_t off = 0;
    auto alloc = [&](size_t bytes) -> void* {
        void* p = ws + off;
        off += (bytes + 255) & ~(size_t)255;
        return p;
    };
    u16* X = (u16*)alloc((size_t)N * 256 * 2);  // 128 MiB
    int* rp = (int*)alloc((size_t)N * 4);
    int2* est = (int2*)alloc((size_t)E * 8);
    float* dinv = (float*)alloc((size_t)N * 4);
    int* gstart = (int*)alloc((size_t)(G + 1) * 4);
    float* stats = (float*)alloc(512 * 4);
    float* stbuf = (float*)alloc(512 * 4);
    float* cvec = (float*)alloc(256 * 4);
    u16* Wp = (u16*)alloc(256 * 256 * 2);
    int* bsum = (int*)alloc(1024 * 4);
    float* weff = (float*)alloc(513 * 4);
    size_t offR = off;

    size_t halfB = ((size_t)N * 128 * 2 + 255) & ~(size_t)255;  // 64 MiB
    size_t s2sR = 0;
    {
        size_t t = 0;
        auto sz = [&](size_t b) { t += (b + 255) & ~(size_t)255; };
        sz((size_t)1024 * 768 * 2);  // Wcat
        sz(1024 * 4);                // bcat
        sz((size_t)G * 768 * 2);     // qsh
        sz((size_t)G * 1024 * 2);    // gates
        sz((size_t)G * 256 * 4);     // hsb
        sz((size_t)G * 256 * 4);     // csb
        s2sR = t;
    }
    size_t needA = offR + halfB + s2sR;                   // Y live through s2s
    size_t needB = offR + (halfB > s2sR ? halfB : s2sR);  // s2s aliases Y
    bool tierA = ws_size >= needA;
    if (!tierA && ws_size < needB) {
        k_diagf<<<(G + 255) / 256, 256, 0, stream>>>((float*)d_out, G, 12345.0f);
        return;
    }
    u16* Y = (u16*)(ws + offR);
    size_t s2sBase = tierA ? offR + halfB : offR;
    size_t o2 = s2sBase;
    auto alloc2 = [&](size_t bytes) -> void* {
        void* p = ws + o2;
        o2 += (bytes + 255) & ~(size_t)255;
        return p;
    };
    u16* Wcat = (u16*)alloc2((size_t)1024 * 768 * 2);
    float* bcat = (float*)alloc2(1024 * 4);
    u16* qsh = (u16*)alloc2((size_t)G * 768 * 2);
    u16* gates = (u16*)alloc2((size_t)G * 1024 * 2);
    float* hsb = (float*)alloc2((size_t)G * 256 * 4);
    float* csb = (float*)alloc2((size_t)G * 256 * 4);

    // embed + segment starts + CSR
    k_embed<<<N / 8, 256, 0, stream>>>(x, atom_emb, X, N);
    k_gstart<<<(N + 255) / 256, 256, 0, stream>>>(batch, gstart, N, G);
    k_zero_int<<<(N + 255) / 256, 256, 0, stream>>>(rp, N);
    k_count<<<(E + 255) / 256, 256, 0, stream>>>(tgtp, rp, E);
    k_dinv<<<(N + 255) / 256, 256, 0, stream>>>(rp, dinv, N);
    int nb1 = (N + 1023) / 1024;
    k_scan1<<<nb1, 256, 0, stream>>>(rp, bsum, N);
    k_scan2<<<1, 256, 0, stream>>>(bsum, nb1);
    k_scan3<<<(N + 255) / 256, 256, 0, stream>>>(rp, bsum, N);
    k_fill<<<(E + 255) / 256, 256, 0, stream>>>(srcp, tgtp, rp, dinv, est, E);

    int gipb = N / 64;
    int cpb = (N * 16 + 255) / 256;
    int aggb = (N / 4 + 15) / 16;

    // conv1: GEMM X->X; agg h0: X+0 -> Y; agg h1: X+128 -> X+0. State: (Y/128, X+0/256).
    k_cvtW<<<256, 256, 0, stream>>>(W1, Wp, 65536);
    k_zero_f32<<<2, 256, 0, stream>>>(stats, 512);
    k_gemm<<<gipb, 256, 0, stream>>>(X, 256, X + 128, 256, Wp, nullptr, X, N);
    k_aggh<true><<<aggb, 256, 0, stream>>>(X, 256, Y, 128, rp, est, dinv, b1, stats, stats + 256, N);
    k_aggh<true><<<aggb, 256, 0, stream>>>(X + 128, 256, X, 256, rp, est, dinv, b1 + 128, stats + 128, stats + 384, N);
    k_bnparam<<<1, 256, 0, stream>>>(stats, gamma, beta, stbuf, N);

    // conv2
    k_fold<<<256, 256, 0, stream>>>(W2, stbuf, Wp, cvec);
    k_zero_f32<<<2, 256, 0, stream>>>(stats, 512);
    k_gemm<<<gipb, 256, 0, stream>>>(Y, 128, X, 256, Wp, cvec, X, N);
    k_aggh<true><<<aggb, 256, 0, stream>>>(X, 256, Y, 128, rp, est, dinv, b2, stats, stats + 256, N);
    k_aggh<true><<<aggb, 256, 0, stream>>>(X + 128, 256, X, 256, rp, est, dinv, b2 + 128, stats + 128, stats + 384, N);
    k_bnparam<<<1, 256, 0, stream>>>(stats, gamma, beta, stbuf, N);

    // conv3
    k_fold<<<256, 256, 0, stream>>>(W3, stbuf, Wp, cvec);
    k_gemm<<<gipb, 256, 0, stream>>>(Y, 128, X, 256, Wp, cvec, X, N);
    const u16 *h3lo, *h3hi;
    int h3ls, h3hs;
    if (tierA) {
        k_aggh<false><<<aggb, 256, 0, stream>>>(X, 256, Y, 128, rp, est, dinv, b3, nullptr, nullptr, N);
        k_aggh<false><<<aggb, 256, 0, stream>>>(X + 128, 256, X, 256, rp, est, dinv, b3 + 128, nullptr, nullptr, N);
        h3lo = Y; h3ls = 128; h3hi = X; h3hs = 256;
    } else {
        k_copyh<<<cpb, 256, 0, stream>>>(X, Y, N);
        k_aggh<false><<<aggb, 256, 0, stream>>>(Y, 128, X, 256, rp, est, dinv, b3, nullptr, nullptr, N);
        k_copyh<<<cpb, 256, 0, stream>>>(X + 128, Y, N);
        k_aggh<false><<<aggb, 256, 0, stream>>>(Y, 128, X + 128, 256, rp, est, dinv, b3 + 128, nullptr, nullptr, N);
        h3lo = X; h3ls = 256; h3hi = X + 128; h3hs = 256;
    }

    // set2set
    k_wcat<<<1024, 256, 0, stream>>>(Wi, Wh, bi, bh, Wcat, bcat);
    k_zero_f32<<<(G * 256 + 255) / 256, 256, 0, stream>>>(csb, G * 256);
    dim3 ggates(G / 128, 8);
    for (int s = 0; s < 4; ++s) {
        if (s == 0)
            k_gates0<<<(G + 7) / 8, 256, 0, stream>>>(bcat, gates, G);
        else
            k_gemmf<<<ggates, 256, 0, stream>>>(qsh, Wcat, bcat, gates, G, 768, 1024);
        k_lstm<<<(G * 256 + 255) / 256, 256, 0, stream>>>(gates, csb, hsb, qsh, G);
        k_attn2<<<(G + 3) / 4, 256, 0, stream>>>(h3lo, h3ls, h3hi, h3hs, hsb, gstart, qsh, G);
    }
    k_wfold<<<2, 256, 0, stream>>>(l1W, l1b, l2W, l2b, weff);
    k_final2<<<(G + 3) / 4, 256, 0, stream>>>(qsh, weff, (float*)d_out, G);
}

// Round 16
// 1301.163 us; speedup vs baseline: 1.1424x; 1.0949x over previous
//
#include <hip/hip_runtime.h>
#include <hip/hip_bf16.h>
#include <math.h>

using u16 = unsigned short;
typedef __attribute__((ext_vector_type(8))) short short8;
typedef __attribute__((ext_vector_type(8))) _Float16 half8;
typedef __attribute__((ext_vector_type(4))) float f32x4;
typedef __attribute__((ext_vector_type(4))) u16 u16x4;

__device__ __constant__ int c_OFF[9] = {0, 119, 123, 135, 147, 157, 163, 169, 171};

__device__ __forceinline__ float h2f(u16 u) {
    _Float16 h;
    __builtin_memcpy(&h, &u, 2);
    return (float)h;
}
__device__ __forceinline__ u16 f2h(float f) {
    _Float16 h = (_Float16)f;
    u16 u;
    __builtin_memcpy(&u, &h, 2);
    return u;
}
__device__ __forceinline__ float sigf(float x) { return 1.f / (1.f + expf(-x)); }

// ---------------- diagnostics ----------------
__global__ void k_diagf(float* out, int G, float val) {
    int i = blockIdx.x * 256 + threadIdx.x;
    if (i < G) out[i] = val;
}

// ---------------- zero helpers ----------------
__global__ void k_zero_f32(float* p, int n) {
    int i = blockIdx.x * 256 + threadIdx.x;
    if (i < n) p[i] = 0.f;
}
__global__ void k_zero_int(int* p, int n) {
    int i = blockIdx.x * 256 + threadIdx.x;
    if (i < n) p[i] = 0;
}

// ---------------- fp32 -> fp16 convert ----------------
__global__ void k_cvtW(const float* __restrict__ src, u16* __restrict__ dst, int n) {
    int i = blockIdx.x * 256 + threadIdx.x;
    if (i < n) dst[i] = f2h(src[i]);
}

// ---------------- atom encoder: 8 nodes/block, 8 cols/thread, vectorized ----------------
__global__ __launch_bounds__(256) void k_embed(const int* __restrict__ x,
                                               const float* __restrict__ emb,
                                               u16* __restrict__ out, int N) {
    __shared__ int rows[72];
    int nb = blockIdx.x * 8;
    int tid = threadIdx.x;
    if (tid < 72) rows[tid] = x[(size_t)nb * 9 + tid] + c_OFF[tid % 9];
    __syncthreads();
    int ln = tid >> 5;
    int c8 = (tid & 31) * 8;
    float s0 = 0.f, s1 = 0.f, s2 = 0.f, s3 = 0.f, s4 = 0.f, s5 = 0.f, s6 = 0.f, s7 = 0.f;
#pragma unroll
    for (int c = 0; c < 9; ++c) {
        int r = rows[ln * 9 + c];
        f32x4 a = *(const f32x4*)&emb[r * 256 + c8];
        f32x4 b = *(const f32x4*)&emb[r * 256 + c8 + 4];
        s0 += a[0]; s1 += a[1]; s2 += a[2]; s3 += a[3];
        s4 += b[0]; s5 += b[1]; s6 += b[2]; s7 += b[3];
    }
    short8 o;
    o[0] = (short)f2h(s0); o[1] = (short)f2h(s1); o[2] = (short)f2h(s2); o[3] = (short)f2h(s3);
    o[4] = (short)f2h(s4); o[5] = (short)f2h(s5); o[6] = (short)f2h(s6); o[7] = (short)f2h(s7);
    *(short8*)&out[(size_t)(nb + ln) * 256 + c8] = o;
}

// ---------------- graph segment starts from sorted batch ----------------
__global__ void k_gstart(const int* __restrict__ batch, int* __restrict__ gstart, int N, int G) {
    int i = blockIdx.x * 256 + threadIdx.x;
    if (i >= N) return;
    int b = batch[i];
    if (i == 0) {
        for (int g = 0; g <= b; ++g) gstart[g] = 0;
    } else {
        int p = batch[i - 1];
        for (int g = p + 1; g <= b; ++g) gstart[g] = i;
    }
    if (i == N - 1) {
        for (int g = b + 1; g <= G; ++g) gstart[g] = N;
    }
}

// ---------------- CSR build (in-place in rp) ----------------
__global__ void k_count(const int* __restrict__ tgt, int* rp, int E) {
    int e = blockIdx.x * 256 + threadIdx.x;
    if (e < E) atomicAdd(&rp[tgt[e]], 1);
}

__global__ void k_dinv(const int* __restrict__ cnt, float* __restrict__ dinv, int N) {
    int i = blockIdx.x * 256 + threadIdx.x;
    if (i < N) dinv[i] = rsqrtf((float)cnt[i] + 1.f);
}

__global__ void k_scan1(int* __restrict__ rp, int* __restrict__ bsum, int N) {
    int t = threadIdx.x;
    int base = blockIdx.x * 1024 + t * 4;
    int v0 = 0, v1 = 0, v2 = 0, v3 = 0;
    if (base + 3 < N) {
        v0 = rp[base]; v1 = rp[base + 1]; v2 = rp[base + 2]; v3 = rp[base + 3];
    } else {
        if (base < N) v0 = rp[base];
        if (base + 1 < N) v1 = rp[base + 1];
        if (base + 2 < N) v2 = rp[base + 2];
    }
    int s = v0 + v1 + v2 + v3;
    int lane = t & 63, w = t >> 6;
    int x = s;
    for (int o = 1; o < 64; o <<= 1) {
        int y = __shfl_up(x, o, 64);
        if (lane >= o) x += y;
    }
    __shared__ int wsum[4];
    if (lane == 63) wsum[w] = x;
    __syncthreads();
    int woff = 0;
    for (int i = 0; i < w; ++i) woff += wsum[i];
    int excl = woff + x - s;
    if (base < N) rp[base] = excl;
    if (base + 1 < N) rp[base + 1] = excl + v0;
    if (base + 2 < N) rp[base + 2] = excl + v0 + v1;
    if (base + 3 < N) rp[base + 3] = excl + v0 + v1 + v2;
    if (t == 255) bsum[blockIdx.x] = wsum[0] + wsum[1] + wsum[2] + wsum[3];
}

__global__ void k_scan2(int* bsum, int nb) {
    int t = threadIdx.x;
    int s = (t < nb) ? bsum[t] : 0;
    int lane = t & 63, w = t >> 6;
    int x = s;
    for (int o = 1; o < 64; o <<= 1) {
        int y = __shfl_up(x, o, 64);
        if (lane >= o) x += y;
    }
    __shared__ int wsum[4];
    if (lane == 63) wsum[w] = x;
    __syncthreads();
    int woff = 0;
    for (int i = 0; i < w; ++i) woff += wsum[i];
    if (t < nb) bsum[t] = woff + x - s;
}

__global__ void k_scan3(int* __restrict__ rp, const int* __restrict__ bsum, int N) {
    int i = blockIdx.x * 256 + threadIdx.x;
    if (i < N) rp[i] += bsum[i >> 10];
}

// fill with packed (src, norm); afterwards rp[n] = end(n), start(n) = rp[n-1]
__global__ void k_fill(const int* __restrict__ src, const int* __restrict__ tgt,
                       int* __restrict__ rp, const float* __restrict__ dinv,
                       int2* __restrict__ est, int E) {
    int e = blockIdx.x * 256 + threadIdx.x;
    if (e < E) {
        int t = tgt[e];
        int s = src[e];
        int p = atomicAdd(&rp[t], 1);
        est[p] = make_int2(s, __float_as_int(dinv[s] * dinv[t]));
    }
}

// ---------------- GEMM: out[64 rows of X] <- A(from two half-buffers) @ Wp^T (+cvec) ----------------
__global__ __launch_bounds__(256, 3) void k_gemm(const u16* __restrict__ p0, int rs0,
                                                 const u16* __restrict__ p1, int rs1,
                                                 const u16* __restrict__ W,
                                                 const float* __restrict__ cvec,
                                                 u16* __restrict__ out, int N) {
    __shared__ u16 As[64][260];
    __shared__ u16 Ws[256][36];
    int r0 = blockIdx.x * 64;
    int tid = threadIdx.x, lane = tid & 63, w = tid >> 6;
#pragma unroll
    for (int i = 0; i < 8; ++i) {
        int chunk = i * 256 + tid;
        int r = chunk >> 5, c8 = chunk & 31;
        const u16* sp = (c8 < 16) ? &p0[(size_t)(r0 + r) * rs0 + c8 * 8]
                                  : &p1[(size_t)(r0 + r) * rs1 + (c8 - 16) * 8];
        *(short8*)&As[r][c8 * 8] = *(const short8*)sp;
    }
    f32x4 acc[16];
#pragma unroll
    for (int o = 0; o < 16; ++o) acc[o] = f32x4{0.f, 0.f, 0.f, 0.f};
    for (int k0 = 0; k0 < 256; k0 += 32) {
        __syncthreads();
#pragma unroll
        for (int i = 0; i < 4; ++i) {
            int chunk = i * 256 + tid;
            int r = chunk >> 2, c8 = chunk & 3;
            *(short8*)&Ws[r][c8 * 8] = *(const short8*)&W[(size_t)r * 256 + k0 + c8 * 8];
        }
        __syncthreads();
        half8 af = *(const half8*)&As[w * 16 + (lane & 15)][k0 + (lane >> 4) * 8];
#pragma unroll
        for (int o = 0; o < 16; ++o) {
            half8 wf = *(const half8*)&Ws[o * 16 + (lane & 15)][(lane >> 4) * 8];
            acc[o] = __builtin_amdgcn_mfma_f32_16x16x32_f16(af, wf, acc[o], 0, 0, 0);
        }
    }
    __syncthreads();
#pragma unroll
    for (int o = 0; o < 16; ++o) {
        int col = o * 16 + (lane & 15);
        float cv = cvec ? cvec[col] : 0.f;
#pragma unroll
        for (int r = 0; r < 4; ++r) {
            int row = w * 16 + (lane >> 4) * 4 + r;
            As[row][col] = f2h(acc[o][r] + cv);
        }
    }
    __syncthreads();
#pragma unroll
    for (int i = 0; i < 8; ++i) {
        int chunk = i * 256 + tid;
        int r = chunk >> 5, c8 = chunk & 31;
        *(short8*)&out[(size_t)(r0 + r) * 256 + c8 * 8] = *(const short8*)&As[r][c8 * 8];
    }
}

// ---------------- half aggregation: est BURST + register-address gathers ----------------
template <bool RS>
__global__ __launch_bounds__(256) void k_aggh(const u16* __restrict__ src, int srs,
                                              u16* __restrict__ dst, int drs,
                                              const int* __restrict__ rp,
                                              const int2* __restrict__ est,
                                              const float* __restrict__ dinv,
                                              const float* __restrict__ biasH,
                                              float* __restrict__ statS,
                                              float* __restrict__ statQ, int N) {
    int l = threadIdx.x & 15;
    int sub = blockIdx.x * 16 + (threadIdx.x >> 4);
    int n0 = sub * 4;
    float bv[8];
#pragma unroll
    for (int k = 0; k < 8; ++k) bv[k] = biasH[l * 8 + k];
    float ss[8] = {}, qq[8] = {};
    if (n0 < N) {
        int r0 = n0 ? rp[n0 - 1] : 0;
        int r1 = rp[n0], r2 = rp[n0 + 1], r3 = rp[n0 + 2], r4 = rp[n0 + 3];
        float d0 = dinv[n0], d1 = dinv[n0 + 1], d2 = dinv[n0 + 2], d3 = dinv[n0 + 3];
        short8 h0 = *(const short8*)&src[(size_t)n0 * srs + l * 8];
        short8 h1 = *(const short8*)&src[(size_t)(n0 + 1) * srs + l * 8];
        short8 h2 = *(const short8*)&src[(size_t)(n0 + 2) * srs + l * 8];
        short8 h3 = *(const short8*)&src[(size_t)(n0 + 3) * srs + l * 8];
        float a0[8], a1[8], a2[8], a3[8];
#pragma unroll
        for (int k = 0; k < 8; ++k) {
            a0[k] = h2f((u16)h0[k]) * d0 * d0 + bv[k];
            a1[k] = h2f((u16)h1[k]) * d1 * d1 + bv[k];
            a2[k] = h2f((u16)h2[k]) * d2 * d2 + bv[k];
            a3[k] = h2f((u16)h3[k]) * d3 * d3 + bv[k];
        }
        for (int base = r0; base < r4; base += 16) {
            int gl = base + l;
            int2 eL = est[gl < r4 ? gl : r4 - 1];
#pragma unroll
            for (int j = 0; j < 16; ++j) {
                int gj = base + j;
                if (gj < r4) {
                    int sx = __shfl(eL.x, j, 16);
                    float nr = __int_as_float(__shfl(eL.y, j, 16));
                    float m0 = (gj < r1) ? nr : 0.f;
                    float m1 = (gj >= r1 && gj < r2) ? nr : 0.f;
                    float m2 = (gj >= r2 && gj < r3) ? nr : 0.f;
                    float m3 = (gj >= r3) ? nr : 0.f;
                    short8 v = *(const short8*)&src[(size_t)sx * srs + l * 8];
#pragma unroll
                    for (int k = 0; k < 8; ++k) {
                        float f = h2f((u16)v[k]);
                        a0[k] += f * m0;
                        a1[k] += f * m1;
                        a2[k] += f * m2;
                        a3[k] += f * m3;
                    }
                }
            }
        }
        short8 o0, o1, o2, o3;
#pragma unroll
        for (int k = 0; k < 8; ++k) {
            if (RS) {
                a0[k] = fmaxf(a0[k], 0.f); a1[k] = fmaxf(a1[k], 0.f);
                a2[k] = fmaxf(a2[k], 0.f); a3[k] = fmaxf(a3[k], 0.f);
                ss[k] += a0[k] + a1[k] + a2[k] + a3[k];
                qq[k] += a0[k] * a0[k] + a1[k] * a1[k] + a2[k] * a2[k] + a3[k] * a3[k];
            }
            o0[k] = (short)f2h(a0[k]); o1[k] = (short)f2h(a1[k]);
            o2[k] = (short)f2h(a2[k]); o3[k] = (short)f2h(a3[k]);
        }
        *(short8*)&dst[(size_t)n0 * drs + l * 8] = o0;
        *(short8*)&dst[(size_t)(n0 + 1) * drs + l * 8] = o1;
        *(short8*)&dst[(size_t)(n0 + 2) * drs + l * 8] = o2;
        *(short8*)&dst[(size_t)(n0 + 3) * drs + l * 8] = o3;
    }
    if (RS) {
        __shared__ float sh[256];
        int t = threadIdx.x;
        sh[t] = 0.f;
        __syncthreads();
#pragma unroll
        for (int k = 0; k < 8; ++k) {
            atomicAdd(&sh[l * 8 + k], ss[k]);
            atomicAdd(&sh[128 + l * 8 + k], qq[k]);
        }
        __syncthreads();
        if (t < 128)
            atomicAdd(&statS[t], sh[t]);
        else
            atomicAdd(&statQ[t - 128], sh[t]);
    }
}

// ---------------- half snapshot copy (tier B) ----------------
__global__ void k_copyh(const u16* __restrict__ src, u16* __restrict__ dst, int N) {
    int i = blockIdx.x * 256 + threadIdx.x;
    if (i >= N * 16) return;
    int n = i >> 4, c8 = (i & 15) * 8;
    *(short8*)&dst[(size_t)n * 128 + c8] = *(const short8*)&src[(size_t)n * 256 + c8];
}

__global__ void k_bnparam(const float* __restrict__ stats, const float* __restrict__ gamma,
                          const float* __restrict__ beta, float* __restrict__ st, int N) {
    int d = threadIdx.x;
    float inv = 1.f / (float)N;
    float mu = stats[d] * inv;
    float var = fmaxf(stats[256 + d] * inv - mu * mu, 0.f);
    float sc = gamma[d] * rsqrtf(var + 1e-5f);
    st[d] = sc;
    st[256 + d] = beta[d] - mu * sc;
}

__global__ void k_fold(const float* __restrict__ W, const float* __restrict__ st,
                       u16* __restrict__ Wp, float* __restrict__ cvec) {
    __shared__ float red[256];
    int o = blockIdx.x, k = threadIdx.x;
    float w = W[o * 256 + k];
    Wp[o * 256 + k] = f2h(w * st[k]);
    red[k] = w * st[256 + k];
    __syncthreads();
    for (int s = 128; s > 0; s >>= 1) {
        if (k < s) red[k] += red[k + s];
        __syncthreads();
    }
    if (k == 0) cvec[o] = red[0];
}

// ---------------- set2set GEMM: C[M,O](f16) = A[M,K](f16) @ W[O,K](f16)^T + cvec ----------------
__global__ __launch_bounds__(256, 2) void k_gemmf(const u16* __restrict__ A,
                                                  const u16* __restrict__ W,
                                                  const float* __restrict__ cvec,
                                                  u16* __restrict__ C, int M, int K, int O) {
    const int PAD = 8;
    __shared__ u16 As[128][64 + PAD];
    __shared__ u16 Ws[128][64 + PAD];
    int tM = blockIdx.x, tO = blockIdx.y;
    int tid = threadIdx.x;
    int lane = tid & 63, wid = tid >> 6;
    int wM = wid & 1, wO = wid >> 1;
    f32x4 acc[4][4] = {};
    size_t rowA0 = (size_t)tM * 128, rowW0 = (size_t)tO * 128;
    for (int k0 = 0; k0 < K; k0 += 64) {
#pragma unroll
        for (int i = 0; i < 4; ++i) {
            int chunk = tid + i * 256;
            int r = chunk >> 3, c16 = chunk & 7;
            *(short8*)&As[r][c16 * 8] = *(const short8*)&A[(rowA0 + r) * K + k0 + c16 * 8];
            *(short8*)&Ws[r][c16 * 8] = *(const short8*)&W[(rowW0 + r) * K + k0 + c16 * 8];
        }
        __syncthreads();
#pragma unroll
        for (int ks = 0; ks < 2; ++ks) {
            half8 af[4], wf[4];
#pragma unroll
            for (int m = 0; m < 4; ++m)
                af[m] = *(const half8*)&As[wM * 64 + m * 16 + (lane & 15)][ks * 32 + (lane >> 4) * 8];
#pragma unroll
            for (int o = 0; o < 4; ++o)
                wf[o] = *(const half8*)&Ws[wO * 64 + o * 16 + (lane & 15)][ks * 32 + (lane >> 4) * 8];
#pragma unroll
            for (int m = 0; m < 4; ++m)
#pragma unroll
                for (int o = 0; o < 4; ++o)
                    acc[m][o] = __builtin_amdgcn_mfma_f32_16x16x32_f16(af[m], wf[o], acc[m][o], 0, 0, 0);
        }
        __syncthreads();
    }
#pragma unroll
    for (int m = 0; m < 4; ++m) {
        int R0 = tM * 128 + wM * 64 + m * 16 + (lane >> 4) * 4;
#pragma unroll
        for (int o = 0; o < 4; ++o) {
            int Cc = tO * 128 + wO * 64 + o * 16 + (lane & 15);
            float cv = cvec[Cc];
#pragma unroll
            for (int r = 0; r < 4; ++r)
                C[(size_t)(R0 + r) * O + Cc] = f2h(acc[m][o][r] + cv);
        }
    }
}

// ---------------- set2set pieces ----------------
__global__ void k_wcat(const float* __restrict__ Wi, const float* __restrict__ Wh,
                       const float* __restrict__ bi, const float* __restrict__ bh,
                       u16* __restrict__ Wcat, float* __restrict__ bcat) {
    int o = blockIdx.x;
    int t = threadIdx.x;
    for (int c = t; c < 512; c += 256) Wcat[(size_t)o * 768 + c] = f2h(Wi[(size_t)o * 512 + c]);
    if (t < 256) Wcat[(size_t)o * 768 + 512 + t] = f2h(Wh[(size_t)o * 256 + t]);
    if (t == 0) bcat[o] = bi[o] + bh[o];
}

// step-0 gates: q_star = hs = 0, so gates row = bcat (broadcast)
__global__ void k_gates0(const float* __restrict__ bcat, u16* __restrict__ gates, int G) {
    __shared__ u16 bh[1024];
    int t = threadIdx.x;
#pragma unroll
    for (int j = 0; j < 4; ++j) bh[t + j * 256] = f2h(bcat[t + j * 256]);
    __syncthreads();
    int g0 = blockIdx.x * 8;
    for (int r = 0; r < 8; ++r) {
        int g = g0 + r;
        if (g >= G) return;
#pragma unroll
        for (int j = 0; j < 4; ++j)
            gates[(size_t)g * 1024 + t + j * 256] = bh[t + j * 256];
    }
}

__global__ void k_lstm(const u16* __restrict__ gates, float* __restrict__ cs,
                       float* __restrict__ hsb, u16* __restrict__ qsh, int G) {
    int idx = blockIdx.x * 256 + threadIdx.x;
    if (idx >= G * 256) return;
    int g = idx >> 8, d = idx & 255;
    const u16* gt = &gates[(size_t)g * 1024];
    float gi = h2f(gt[d]), gf = h2f(gt[256 + d]), gg = h2f(gt[512 + d]), go = h2f(gt[768 + d]);
    float c = sigf(gf) * cs[idx] + sigf(gi) * tanhf(gg);
    float hh = sigf(go) * tanhf(c);
    cs[idx] = c;
    hsb[idx] = hh;
    u16 hb = f2h(hh);
    qsh[(size_t)g * 768 + d] = hb;
    qsh[(size_t)g * 768 + 512 + d] = hb;
}

// ---------------- attention: SINGLE-PASS online softmax, one wave per graph ----------------
__global__ __launch_bounds__(256) void k_attn3(const u16* __restrict__ lo, int lstr,
                                               const u16* __restrict__ hi, int hstr,
                                               const float* __restrict__ hs,
                                               const int* __restrict__ gstart,
                                               u16* __restrict__ qsh, int G) {
    int wid = threadIdx.x >> 6, lane = threadIdx.x & 63;
    int g = blockIdx.x * 4 + wid;
    if (g >= G) return;
    int start = gstart[g], end = gstart[g + 1];

    const u16* base = (lane < 32) ? lo : hi;
    size_t stride = (lane < 32) ? lstr : hstr;
    int coff = (lane < 32) ? lane * 4 : (lane - 32) * 4;

    f32x4 q = *(const f32x4*)&hs[(size_t)g * 256 + lane * 4];
    float m = -INFINITY, z = 0.f;
    float r0 = 0.f, r1 = 0.f, r2 = 0.f, r3 = 0.f;

    for (int i = start; i < end; ++i) {
        u16x4 hv = *(const u16x4*)&base[(size_t)i * stride + coff];
        float f0 = h2f(hv[0]), f1 = h2f(hv[1]), f2 = h2f(hv[2]), f3 = h2f(hv[3]);
        float e = f0 * q[0] + f1 * q[1] + f2 * q[2] + f3 * q[3];
        e += __shfl_xor(e, 32, 64);
        e += __shfl_xor(e, 16, 64);
        e += __shfl_xor(e, 8, 64);
        e += __shfl_xor(e, 4, 64);
        e += __shfl_xor(e, 2, 64);
        e += __shfl_xor(e, 1, 64);
        if (e > m) {  // wave-uniform (e identical across lanes after reduce)
            float rf = expf(m - e);  // first time: exp(-inf)=0 zeroes the empty state
            z *= rf;
            r0 *= rf; r1 *= rf; r2 *= rf; r3 *= rf;
            m = e;
        }
        float w = expf(e - m);
        z += w;
        r0 += w * f0; r1 += w * f1; r2 += w * f2; r3 += w * f3;
    }
    float inv = (end > start) ? 1.f / fmaxf(z, 1e-30f) : 0.f;
    u16x4 o;
    o[0] = f2h(r0 * inv);
    o[1] = f2h(r1 * inv);
    o[2] = f2h(r2 * inv);
    o[3] = f2h(r3 * inv);
    int qcol = (lane < 32) ? lane * 4 : 128 + (lane - 32) * 4;
    *(u16x4*)&qsh[(size_t)g * 768 + 256 + qcol] = o;
}

// lin1/lin2 compose
__global__ void k_wfold(const float* __restrict__ l1W, const float* __restrict__ l1b,
                        const float* __restrict__ l2W, const float* __restrict__ l2b,
                        float* __restrict__ weff) {
    int c = blockIdx.x * 256 + threadIdx.x;
    if (c < 512) {
        float s = 0.f;
        for (int t = 0; t < 128; ++t) s += l2W[t] * l1W[(size_t)t * 512 + c];
        weff[c] = s;
    }
    if (c == 0) {
        float b = l2b[0];
        for (int t = 0; t < 128; ++t) b += l2W[t] * l1b[t];
        weff[512] = b;
    }
}

__global__ __launch_bounds__(256) void k_final2(const u16* __restrict__ qsh,
                                                const float* __restrict__ weff,
                                                float* __restrict__ out, int G) {
    __shared__ float wsm[513];
    int tid = threadIdx.x;
    for (int j = tid; j < 513; j += 256) wsm[j] = weff[j];
    __syncthreads();
    int g = blockIdx.x * 4 + (tid >> 6);
    int lane = tid & 63;
    if (g >= G) return;
    const u16* qp = &qsh[(size_t)g * 768];
    float s = 0.f;
#pragma unroll
    for (int j = 0; j < 8; ++j) s += h2f(qp[lane * 8 + j]) * wsm[lane * 8 + j];
    for (int off = 32; off; off >>= 1) s += __shfl_xor(s, off, 64);
    if (lane == 0) out[g] = sigf(s + wsm[512]);
}

// ---------------- host ----------------
extern "C" void kernel_launch(void* const* d_in, const int* in_sizes, int n_in,
                              void* d_out, int out_size, void* d_ws, size_t ws_size,
                              hipStream_t stream) {
    const int* x = (const int*)d_in[0];
    const int* ei = (const int*)d_in[1];
    const int* batch = (const int*)d_in[2];
    const float* atom_emb = (const float*)d_in[4];
    const float* W1 = (const float*)d_in[5];
    const float* b1 = (const float*)d_in[6];
    const float* W2 = (const float*)d_in[7];
    const float* b2 = (const float*)d_in[8];
    const float* W3 = (const float*)d_in[9];
    const float* b3 = (const float*)d_in[10];
    const float* gamma = (const float*)d_in[11];
    const float* beta = (const float*)d_in[12];
    const float* Wi = (const float*)d_in[13];
    const float* Wh = (const float*)d_in[14];
    const float* bi = (const float*)d_in[15];
    const float* bh = (const float*)d_in[16];
    const float* l1W = (const float*)d_in[17];
    const float* l1b = (const float*)d_in[18];
    const float* l2W = (const float*)d_in[19];
    const float* l2b = (const float*)d_in[20];

    const int N = in_sizes[0] / 9;
    const int E = in_sizes[1] / 2;
    const int G = out_size;
    const int* srcp = ei;
    const int* tgtp = ei + E;

    char* ws = (char*)d_ws;
    size_t off = 0;
    auto alloc = [&](size_t bytes) -> void* {
        void* p = ws + off;
        off += (bytes + 255) & ~(size_t)255;
        return p;
    };
    u16* X = (u16*)alloc((size_t)N * 256 * 2);  // 128 MiB
    int* rp = (int*)alloc((size_t)N * 4);
    int2* est = (int2*)alloc((size_t)E * 8);
    float* dinv = (float*)alloc((size_t)N * 4);
    int* gstart = (int*)alloc((size_t)(G + 1) * 4);
    float* stats = (float*)alloc(512 * 4);
    float* stbuf = (float*)alloc(512 * 4);
    float* cvec = (float*)alloc(256 * 4);
    u16* Wp = (u16*)alloc(256 * 256 * 2);
    int* bsum = (int*)alloc(1024 * 4);
    float* weff = (float*)alloc(513 * 4);
    size_t offR = off;

    size_t halfB = ((size_t)N * 128 * 2 + 255) & ~(size_t)255;  // 64 MiB
    size_t s2sR = 0;
    {
        size_t t = 0;
        auto sz = [&](size_t b) { t += (b + 255) & ~(size_t)255; };
        sz((size_t)1024 * 768 * 2);  // Wcat
        sz(1024 * 4);                // bcat
        sz((size_t)G * 768 * 2);     // qsh
        sz((size_t)G * 1024 * 2);    // gates
        sz((size_t)G * 256 * 4);     // hsb
        sz((size_t)G * 256 * 4);     // csb
        s2sR = t;
    }
    size_t needA = offR + halfB + s2sR;                   // Y live through s2s
    size_t needB = offR + (halfB > s2sR ? halfB : s2sR);  // s2s aliases Y
    bool tierA = ws_size >= needA;
    if (!tierA && ws_size < needB) {
        k_diagf<<<(G + 255) / 256, 256, 0, stream>>>((float*)d_out, G, 12345.0f);
        return;
    }
    u16* Y = (u16*)(ws + offR);
    size_t s2sBase = tierA ? offR + halfB : offR;
    size_t o2 = s2sBase;
    auto alloc2 = [&](size_t bytes) -> void* {
        void* p = ws + o2;
        o2 += (bytes + 255) & ~(size_t)255;
        return p;
    };
    u16* Wcat = (u16*)alloc2((size_t)1024 * 768 * 2);
    float* bcat = (float*)alloc2(1024 * 4);
    u16* qsh = (u16*)alloc2((size_t)G * 768 * 2);
    u16* gates = (u16*)alloc2((size_t)G * 1024 * 2);
    float* hsb = (float*)alloc2((size_t)G * 256 * 4);
    float* csb = (float*)alloc2((size_t)G * 256 * 4);

    // embed + segment starts + CSR
    k_embed<<<N / 8, 256, 0, stream>>>(x, atom_emb, X, N);
    k_gstart<<<(N + 255) / 256, 256, 0, stream>>>(batch, gstart, N, G);
    k_zero_int<<<(N + 255) / 256, 256, 0, stream>>>(rp, N);
    k_count<<<(E + 255) / 256, 256, 0, stream>>>(tgtp, rp, E);
    k_dinv<<<(N + 255) / 256, 256, 0, stream>>>(rp, dinv, N);
    int nb1 = (N + 1023) / 1024;
    k_scan1<<<nb1, 256, 0, stream>>>(rp, bsum, N);
    k_scan2<<<1, 256, 0, stream>>>(bsum, nb1);
    k_scan3<<<(N + 255) / 256, 256, 0, stream>>>(rp, bsum, N);
    k_fill<<<(E + 255) / 256, 256, 0, stream>>>(srcp, tgtp, rp, dinv, est, E);

    int gipb = N / 64;
    int cpb = (N * 16 + 255) / 256;
    int aggb = (N / 4 + 15) / 16;

    // conv1: GEMM X->X; agg h0: X+0 -> Y; agg h1: X+128 -> X+0. State: (Y/128, X+0/256).
    k_cvtW<<<256, 256, 0, stream>>>(W1, Wp, 65536);
    k_zero_f32<<<2, 256, 0, stream>>>(stats, 512);
    k_gemm<<<gipb, 256, 0, stream>>>(X, 256, X + 128, 256, Wp, nullptr, X, N);
    k_aggh<true><<<aggb, 256, 0, stream>>>(X, 256, Y, 128, rp, est, dinv, b1, stats, stats + 256, N);
    k_aggh<true><<<aggb, 256, 0, stream>>>(X + 128, 256, X, 256, rp, est, dinv, b1 + 128, stats + 128, stats + 384, N);
    k_bnparam<<<1, 256, 0, stream>>>(stats, gamma, beta, stbuf, N);

    // conv2
    k_fold<<<256, 256, 0, stream>>>(W2, stbuf, Wp, cvec);
    k_zero_f32<<<2, 256, 0, stream>>>(stats, 512);
    k_gemm<<<gipb, 256, 0, stream>>>(Y, 128, X, 256, Wp, cvec, X, N);
    k_aggh<true><<<aggb, 256, 0, stream>>>(X, 256, Y, 128, rp, est, dinv, b2, stats, stats + 256, N);
    k_aggh<true><<<aggb, 256, 0, stream>>>(X + 128, 256, X, 256, rp, est, dinv, b2 + 128, stats + 128, stats + 384, N);
    k_bnparam<<<1, 256, 0, stream>>>(stats, gamma, beta, stbuf, N);

    // conv3
    k_fold<<<256, 256, 0, stream>>>(W3, stbuf, Wp, cvec);
    k_gemm<<<gipb, 256, 0, stream>>>(Y, 128, X, 256, Wp, cvec, X, N);
    const u16 *h3lo, *h3hi;
    int h3ls, h3hs;
    if (tierA) {
        k_aggh<false><<<aggb, 256, 0, stream>>>(X, 256, Y, 128, rp, est, dinv, b3, nullptr, nullptr, N);
        k_aggh<false><<<aggb, 256, 0, stream>>>(X + 128, 256, X, 256, rp, est, dinv, b3 + 128, nullptr, nullptr, N);
        h3lo = Y; h3ls = 128; h3hi = X; h3hs = 256;
    } else {
        k_copyh<<<cpb, 256, 0, stream>>>(X, Y, N);
        k_aggh<false><<<aggb, 256, 0, stream>>>(Y, 128, X, 256, rp, est, dinv, b3, nullptr, nullptr, N);
        k_copyh<<<cpb, 256, 0, stream>>>(X + 128, Y, N);
        k_aggh<false><<<aggb, 256, 0, stream>>>(Y, 128, X + 128, 256, rp, est, dinv, b3 + 128, nullptr, nullptr, N);
        h3lo = X; h3ls = 256; h3hi = X + 128; h3hs = 256;
    }

    // set2set
    k_wcat<<<1024, 256, 0, stream>>>(Wi, Wh, bi, bh, Wcat, bcat);
    k_zero_f32<<<(G * 256 + 255) / 256, 256, 0, stream>>>(csb, G * 256);
    dim3 ggates(G / 128, 8);
    for (int s = 0; s < 4; ++s) {
        if (s == 0)
            k_gates0<<<(G + 7) / 8, 256, 0, stream>>>(bcat, gates, G);
        else
            k_gemmf<<<ggates, 256, 0, stream>>>(qsh, Wcat, bcat, gates, G, 768, 1024);
        k_lstm<<<(G * 256 + 255) / 256, 256, 0, stream>>>(gates, csb, hsb, qsh, G);
        k_attn3<<<(G + 3) / 4, 256, 0, stream>>>(h3lo, h3ls, h3hi, h3hs, hsb, gstart, qsh, G);
    }
    k_wfold<<<2, 256, 0, stream>>>(l1W, l1b, l2W, l2b, weff);
    k_final2<<<(G + 3) / 4, 256, 0, stream>>>(qsh, weff, (float*)d_out, G);
}